// Round 3
// baseline (479.778 us; speedup 1.0000x reference)
//
#include <hip/hip_runtime.h>
#include <math.h>

#define NPTS_PER_BLOCK 2048
#define TS 64
#define TO 96

__device__ __forceinline__ float2 cmul2(float2 a, float2 b){
    return make_float2(fmaf(a.x, b.x, -(a.y*b.y)), fmaf(a.x, b.y, a.y*b.x));
}
// acc += z * t (complex)
__device__ __forceinline__ void cacc(float2& a, float2 z, float2 t){
    a.x = fmaf(z.x, t.x, fmaf(-z.y, t.y, a.x));
    a.y = fmaf(z.x, t.y, fmaf( z.y, t.x, a.y));
}

// ---------------- zero a float4-aligned region (replaces hipMemsetAsync) ---
__global__ void zero_kernel(float4* __restrict__ p, int n4)
{
    int i = blockIdx.x * blockDim.x + threadIdx.x;
    if (i < n4) p[i] = make_float4(0.f, 0.f, 0.f, 0.f);
}

// ---------------- setup: euler matrices, z-contribution, Wres2 transpose ----
// scratch layout (floats): Rm @0 (B*9), zc @256 (B*64), W2T @1280 (4*64*64)
__global__ void setup_kernel(const float* __restrict__ r, const float* __restrict__ z,
                             const float* __restrict__ W0, const float* __restrict__ Wres2,
                             float* __restrict__ scratch, int B)
{
    float* Rm  = scratch;
    float* zc  = scratch + 256;
    float* W2T = scratch + 1280;
    int tid = threadIdx.x;
    if (tid < B){
        float a = r[tid*3+0], bb = r[tid*3+1], c = r[tid*3+2];
        float ca = cosf(a), sa = sinf(a);
        float cb = cosf(bb), sb = sinf(bb);
        float cc = cosf(c), sc = sinf(c);
        float* Rb = Rm + tid*9;
        Rb[0] = ca*cb*cc - sa*sc;  Rb[1] = -ca*cb*sc - sa*cc;  Rb[2] = ca*sb;
        Rb[3] = sa*cb*cc + ca*sc;  Rb[4] = -sa*cb*sc + ca*cc;  Rb[5] = sa*sb;
        Rb[6] = -sb*cc;            Rb[7] = sb*sc;              Rb[8] = cb;
    }
    for (int e = tid; e < B*64; e += 256){
        int b = e >> 6, i = e & 63;
        float acc = 0.f;
        for (int j = 0; j < 16; j++) acc = fmaf(W0[i*19+3+j], z[b*16+j], acc);
        zc[e] = acc;
    }
    // W2T[l][k][i] = Wres2[l][i][k]
    for (int e = tid; e < 4*64*64; e += 256){
        int l = e >> 12, rem = e & 4095, k = rem >> 6, i = rem & 63;
        W2T[e] = Wres2[l*4096 + i*64 + k];
    }
}

// ---------------- per-point residual MLP + rotate/project ------------------
__launch_bounds__(256)
__global__ void decoder_kernel(const float* __restrict__ pos,
                               const float* __restrict__ W0,
                               const float* __restrict__ Wres1,
                               const float* __restrict__ scratch,
                               const float* __restrict__ W1a,
                               const float* __restrict__ W1b,
                               float* __restrict__ out_proj_pos,
                               float* __restrict__ out_pos_d,
                               float* __restrict__ out_res,
                               int N)
{
    const float* __restrict__ Rm  = scratch;
    const float* __restrict__ zc  = scratch + 256;
    const float* __restrict__ W2T = scratch + 1280;

    int b = blockIdx.y;
    int n = blockIdx.x * blockDim.x + threadIdx.x;
    if (n >= N) return;
    float px = pos[n*3+0], py = pos[n*3+1], pz = pos[n*3+2];
    const float* __restrict__ zcb = zc + b*64;

    float h[64];
#pragma unroll
    for (int i = 0; i < 64; i++){
        const float* w = W0 + i*19;
        h[i] = zcb[i] + w[0]*px + w[1]*py + w[2]*pz;
    }

#pragma unroll 1
    for (int l = 0; l < 4; l++){
        const float* __restrict__ w1  = Wres1 + l*4096;
        const float* __restrict__ w2t = W2T  + l*4096;
        float hacc[64];
#pragma unroll
        for (int i = 0; i < 64; i++) hacc[i] = h[i];
#pragma unroll 1
        for (int k = 0; k < 64; k++){
            const float* __restrict__ w1k = w1 + k*64;
            float s = 0.f;
#pragma unroll
            for (int j = 0; j < 64; j++) s = fmaf(w1k[j], h[j], s);
            s = fmaxf(s, 0.f);
            const float* __restrict__ w2k = w2t + k*64;
#pragma unroll
            for (int i = 0; i < 64; i++) hacc[i] = fmaf(w2k[i], s, hacc[i]);
        }
#pragma unroll
        for (int i = 0; i < 64; i++) h[i] = hacc[i];
    }

    float u0 = 0.f, u1 = 0.f, u2 = 0.f;
#pragma unroll
    for (int i = 0; i < 64; i++){
        u0 = fmaf(W1a[i],      h[i], u0);
        u1 = fmaf(W1a[64+i],   h[i], u1);
        u2 = fmaf(W1a[128+i],  h[i], u2);
    }
    u0 = tanhf(u0); u1 = tanhf(u1); u2 = tanhf(u2);
    float r0 = u0*W1b[0] + u1*W1b[1] + u2*W1b[2];
    float r1 = u0*W1b[3] + u1*W1b[4] + u2*W1b[5];
    float r2 = u0*W1b[6] + u1*W1b[7] + u2*W1b[8];
    float pdx = px + r0, pdy = py + r1, pdz = pz + r2;

    const float* Rb = Rm + b*9;
    float q0 = pdx*Rb[0] + pdy*Rb[3] + pdz*Rb[6];
    float q1 = pdx*Rb[1] + pdy*Rb[4] + pdz*Rb[7];

    size_t base = (size_t)b*N + n;
    out_res[base*3+0] = r0;  out_res[base*3+1] = r1;  out_res[base*3+2] = r2;
    out_pos_d[base*3+0] = pdx; out_pos_d[base*3+1] = pdy; out_pos_d[base*3+2] = pdz;
    out_proj_pos[base*2+0] = q0; out_proj_pos[base*2+1] = q1;
}

// ---------------- bilinear splat with LDS privatization --------------------
__launch_bounds__(256)
__global__ void splat_kernel(const float* __restrict__ proj_pos,
                             const float* __restrict__ ampvar,
                             const float* __restrict__ amp,
                             float* __restrict__ proj_im, int N)
{
    __shared__ float tile[2*TS*TS];
    int b = blockIdx.y;
    for (int i = threadIdx.x; i < 2*TS*TS; i += 256) tile[i] = 0.f;
    __syncthreads();

    float ampv = amp[0];
    int n0 = blockIdx.x * NPTS_PER_BLOCK;
    int n1 = min(n0 + NPTS_PER_BLOCK, N);
    for (int n = n0 + (int)threadIdx.x; n < n1; n += 256){
        size_t base = (size_t)b*N + n;
        float cy = proj_pos[base*2+0];
        float cx = proj_pos[base*2+1];
        float e0 = expf(ampvar[n]);
        float e1 = expf(ampvar[N+n]);
        float inv = ampv / (e0 + e1);
        float v0 = e0*inv, v1 = e1*inv;
        float pyf = (cy + 0.5f) * 255.0f;
        float pxf = (cx + 0.5f) * 255.0f;
        float fy0 = floorf(pyf), fx0 = floorf(pxf);
        int iy = (int)fy0, ix = (int)fx0;
        float fy = pyf - fy0, fx = pxf - fx0;
        float wy[2] = {1.f - fy, fy};
        float wx[2] = {1.f - fx, fx};
#pragma unroll
        for (int dy = 0; dy < 2; dy++){
#pragma unroll
            for (int dx = 0; dx < 2; dx++){
                float w = wy[dy]*wx[dx];
                int yi = min(max(iy+dy, 0), 255);
                int xi = min(max(ix+dx, 0), 255);
                int ty = yi - TO, tx = xi - TO;
                if ((unsigned)ty < TS && (unsigned)tx < TS){
                    atomicAdd(&tile[ty*TS + tx],        v0*w);
                    atomicAdd(&tile[TS*TS + ty*TS + tx], v1*w);
                } else {
                    atomicAdd(&proj_im[((size_t)(b*2+0)*256 + yi)*256 + xi], v0*w);
                    atomicAdd(&proj_im[((size_t)(b*2+1)*256 + yi)*256 + xi], v1*w);
                }
            }
        }
    }
    __syncthreads();
    for (int i = threadIdx.x; i < TS*TS; i += 256){
        int ty = i >> 6, tx = i & 63;
        float v = tile[i];
        if (v != 0.f) atomicAdd(&proj_im[((size_t)(b*2+0)*256 + TO+ty)*256 + TO+tx], v);
        v = tile[TS*TS + i];
        if (v != 0.f) atomicAdd(&proj_im[((size_t)(b*2+1)*256 + TO+ty)*256 + TO+tx], v);
    }
}

// ---------------- DFT pass 1: rows, channels packed as complex -------------
__launch_bounds__(256)
__global__ void dft_rows_kernel(const float* __restrict__ proj_im, float2* __restrict__ S)
{
    int b = blockIdx.y, y = blockIdx.x;
    __shared__ float2 row[256];
    int k = threadIdx.x;
    const float* im0 = proj_im + ((size_t)(b*2+0)*256 + y)*256;
    const float* im1 = proj_im + ((size_t)(b*2+1)*256 + y)*256;
    row[k] = make_float2(im0[k], im1[k]);
    __syncthreads();

    float ang = -6.283185307179586f * (float)k / 256.0f;
    float s1,c1,s2,c2,s3,c3,s4,c4;
    sincosf(ang,      &s1, &c1);
    sincosf(2.f*ang,  &s2, &c2);
    sincosf(3.f*ang,  &s3, &c3);
    sincosf(4.f*ang,  &s4, &c4);
    float2 t0 = make_float2(1.f, 0.f), t1 = make_float2(c1, s1);
    float2 t2 = make_float2(c2, s2),   t3 = make_float2(c3, s3);
    float2 tw = make_float2(c4, s4);
    float2 a0 = {0,0}, a1 = {0,0}, a2 = {0,0}, a3 = {0,0};
    for (int x = 0; x < 256; x += 4){
        float2 z0 = row[x], z1 = row[x+1], z2 = row[x+2], z3 = row[x+3];
        cacc(a0, z0, t0); cacc(a1, z1, t1); cacc(a2, z2, t2); cacc(a3, z3, t3);
        t0 = cmul2(t0, tw); t1 = cmul2(t1, tw); t2 = cmul2(t2, tw); t3 = cmul2(t3, tw);
    }
    float2 acc = make_float2(a0.x+a1.x+a2.x+a3.x, a0.y+a1.y+a2.y+a3.y);
    S[((size_t)b*256 + y)*256 + k] = acc;
}

// ---------------- DFT pass 2: columns, IN PLACE ---------------------------
__launch_bounds__(256)
__global__ void dft_cols_kernel(float2* __restrict__ S)
{
    int b = blockIdx.y, kx = blockIdx.x;
    int ky = threadIdx.x;
    __shared__ float2 col[256];
    float2* Sb = S + (size_t)b*65536;
    col[ky] = Sb[(size_t)ky*256 + kx];
    __syncthreads();

    float ang = -6.283185307179586f * (float)ky / 256.0f;
    float s1,c1,s2,c2,s3,c3,s4,c4;
    sincosf(ang,      &s1, &c1);
    sincosf(2.f*ang,  &s2, &c2);
    sincosf(3.f*ang,  &s3, &c3);
    sincosf(4.f*ang,  &s4, &c4);
    float2 t0 = make_float2(1.f, 0.f), t1 = make_float2(c1, s1);
    float2 t2 = make_float2(c2, s2),   t3 = make_float2(c3, s3);
    float2 tw = make_float2(c4, s4);
    float2 a0 = {0,0}, a1 = {0,0}, a2 = {0,0}, a3 = {0,0};
    for (int y = 0; y < 256; y += 4){
        float2 z0 = col[y], z1 = col[y+1], z2 = col[y+2], z3 = col[y+3];
        cacc(a0, z0, t0); cacc(a1, z1, t1); cacc(a2, z2, t2); cacc(a3, z3, t3);
        t0 = cmul2(t0, tw); t1 = cmul2(t1, tw); t2 = cmul2(t2, tw); t3 = cmul2(t3, tw);
    }
    float2 acc = make_float2(a0.x+a1.x+a2.x+a3.x, a0.y+a1.y+a2.y+a3.y);
    Sb[(size_t)ky*256 + kx] = acc;   // Z[b][ky][kx]
}

// ---------------- Hermitian unpack + CTF filter + channel sum --------------
// pairs==1: write interleaved complex into outP (may alias Z — safe, pair
// owner reads both before writing both). pairs==0: write real part only.
__launch_bounds__(256)
__global__ void combine_kernel(const float2* __restrict__ Z,
                               const float* __restrict__ A, const float* __restrict__ Bc,
                               float* __restrict__ outP, int pairs)
{
    int gid = blockIdx.x*256 + threadIdx.x;
    int b = gid >> 16;
    int lin = gid & 65535;
    int ky = lin >> 8, kx = lin & 255;
    int mky = (256 - ky) & 255, mkx = (256 - kx) & 255;
    int mlin = mky*256 + mkx;
    if (lin > mlin) return;   // pair owner only
    const float2* Zb = Z + (size_t)b*65536;
    float2 Zk = Zb[lin];
    float2 Zm = Zb[mlin];
    // F0 = FFT(im0) = (Z + conj(Z[-k]))/2 ; F1 = FFT(im1) = (Z - conj(Z[-k]))/(2i)
    float Er = 0.5f*(Zk.x + Zm.x), Ei = 0.5f*(Zk.y - Zm.y);
    float Or = 0.5f*(Zk.y + Zm.y), Oi = 0.5f*(Zm.x - Zk.x);
    float fy = (ky < 128) ? (float)ky : (float)(ky - 256);
    float fx = (kx < 128) ? (float)kx : (float)(kx - 256);
    float rad = rintf(sqrtf(fy*fy + fx*fx));
    float a0 = A[0], a1 = A[1], b0 = Bc[0], b1 = Bc[1];
    float F0 = a0*a0*expf(-b0*b0*rad);
    float F1 = a1*a1*expf(-b1*b1*rad);
    float2 P = make_float2(fmaf(F0, Er, F1*Or), fmaf(F0, Ei, F1*Oi));
    if (pairs){
        float2* O = (float2*)outP + (size_t)b*65536;
        O[lin] = P;
        if (mlin != lin) O[mlin] = make_float2(P.x, -P.y);
    } else {
        float* O = outP + (size_t)b*65536;
        O[lin] = P.x;
        if (mlin != lin) O[mlin] = P.x;
    }
}

extern "C" void kernel_launch(void* const* d_in, const int* in_sizes, int n_in,
                              void* d_out, int out_size, void* d_ws, size_t ws_size,
                              hipStream_t stream)
{
    const float* z      = (const float*)d_in[0];
    const float* r      = (const float*)d_in[1];
    const float* pos    = (const float*)d_in[2];
    const float* amp    = (const float*)d_in[3];
    const float* ampvar = (const float*)d_in[4];
    const float* W0     = (const float*)d_in[5];
    const float* Wres1  = (const float*)d_in[6];
    const float* Wres2  = (const float*)d_in[7];
    const float* W1a    = (const float*)d_in[8];
    const float* W1b    = (const float*)d_in[9];
    const float* A      = (const float*)d_in[10];
    const float* Bc     = (const float*)d_in[11];

    int B = in_sizes[0] / 16;     // 16
    int N = in_sizes[2] / 3;      // 20000

    size_t nIm = (size_t)B * 65536;          // B*256*256
    // Adaptive output layout: tail chunks have known sizes; whatever remains
    // at the front is the Proj chunk (2*nIm floats if complex stored as
    // re/im pairs, nIm if stored real-only).
    long long tailSz   = (long long)(2*nIm) + 8LL*B*N;       // projim + pos outputs
    long long projSize = (long long)out_size - tailSz;
    int pairs = (projSize >= (long long)(2*nIm)) ? 1 : 0;

    float* out = (float*)d_out;
    float* out_proj    = out;
    float* out_projim  = out + projSize;
    float* out_projpos = out_projim + 2*nIm;          // B*N*2
    float* out_posd    = out_projpos + (size_t)B*N*2; // B*N*3
    float* out_res     = out_posd    + (size_t)B*N*3; // B*N*3

    // Setup scratch (~70KB) lives at the front of the Proj region, which is
    // dead until dft_rows (decoder consumes the scratch before that).
    float* scratch = out_proj;

    // DFT scratch S/Z: Proj region when it holds float pairs (8MB); otherwise
    // d_ws if verified large enough at runtime.
    float2* S;
    if (pairs)                                        S = (float2*)out_proj;
    else if (ws_size >= (size_t)(2*nIm)*sizeof(float)) S = (float2*)d_ws;
    else                                              S = (float2*)out_proj;

    // zero proj_im (kernel, not hipMemsetAsync)
    int n4 = (int)(2*nIm/4);
    zero_kernel<<<(n4 + 255)/256, 256, 0, stream>>>((float4*)out_projim, n4);

    setup_kernel<<<1, 256, 0, stream>>>(r, z, W0, Wres2, scratch, B);

    dim3 dgrid((N + 255)/256, B);
    decoder_kernel<<<dgrid, 256, 0, stream>>>(pos, W0, Wres1, scratch, W1a, W1b,
                                              out_projpos, out_posd, out_res, N);

    dim3 sgrid((N + NPTS_PER_BLOCK - 1)/NPTS_PER_BLOCK, B);
    splat_kernel<<<sgrid, 256, 0, stream>>>(out_projpos, ampvar, amp, out_projim, N);

    dim3 fgrid(256, B);
    dft_rows_kernel<<<fgrid, 256, 0, stream>>>(out_projim, S);
    dft_cols_kernel<<<fgrid, 256, 0, stream>>>(S);
    combine_kernel<<<(int)(nIm/256), 256, 0, stream>>>(S, A, Bc, out_proj, pairs);
}

// Round 4
// 293.577 us; speedup vs baseline: 1.6343x; 1.6343x over previous
//
#include <hip/hip_runtime.h>
#include <math.h>

#define NPTS_PER_BLOCK 2048
#define TS 64
#define TO 96

typedef __attribute__((ext_vector_type(8))) short bf16x8;
typedef __attribute__((ext_vector_type(4))) float f32x4;

__device__ __forceinline__ float2 cmul2(float2 a, float2 b){
    return make_float2(fmaf(a.x, b.x, -(a.y*b.y)), fmaf(a.x, b.y, a.y*b.x));
}
__device__ __forceinline__ void cacc(float2& a, float2 z, float2 t){
    a.x = fmaf(z.x, t.x, fmaf(-z.y, t.y, a.x));
    a.y = fmaf(z.x, t.y, fmaf( z.y, t.x, a.y));
}
// float -> bf16 bits, round-nearest-even (matches v_cvt semantics for normals)
__device__ __forceinline__ unsigned short f2bf(float f){
    unsigned u = __float_as_uint(f);
    unsigned r = u + 0x7FFFu + ((u >> 16) & 1u);
    return (unsigned short)(r >> 16);
}

// ---------------- zero a float4-aligned region -----------------------------
__global__ void zero_kernel(float4* __restrict__ p, int n4)
{
    int i = blockIdx.x * blockDim.x + threadIdx.x;
    if (i < n4) p[i] = make_float4(0.f, 0.f, 0.f, 0.f);
}

// ---------------- setup: euler, z-contribution, bf16 weight conversion -----
// scratch (floats): Rm @0 (B*9), zc @256 (B*64), Wbf @1280 (32768 ushorts:
//   W1bf[4][64][64] then W2bf[4][64][64], row-major [layer][out_row][k])
__global__ void setup_kernel(const float* __restrict__ r, const float* __restrict__ z,
                             const float* __restrict__ W0,
                             const float* __restrict__ Wres1,
                             const float* __restrict__ Wres2,
                             float* __restrict__ scratch, int B)
{
    float* Rm  = scratch;
    float* zc  = scratch + 256;
    unsigned short* W1bf = (unsigned short*)(scratch + 1280);
    unsigned short* W2bf = W1bf + 4*4096;
    int tid = threadIdx.x;
    if (tid < B){
        float a = r[tid*3+0], bb = r[tid*3+1], c = r[tid*3+2];
        float ca = cosf(a), sa = sinf(a);
        float cb = cosf(bb), sb = sinf(bb);
        float cc = cosf(c), sc = sinf(c);
        float* Rb = Rm + tid*9;
        Rb[0] = ca*cb*cc - sa*sc;  Rb[1] = -ca*cb*sc - sa*cc;  Rb[2] = ca*sb;
        Rb[3] = sa*cb*cc + ca*sc;  Rb[4] = -sa*cb*sc + ca*cc;  Rb[5] = sa*sb;
        Rb[6] = -sb*cc;            Rb[7] = sb*sc;              Rb[8] = cb;
    }
    for (int e = tid; e < B*64; e += 256){
        int b = e >> 6, i = e & 63;
        float acc = 0.f;
        for (int j = 0; j < 16; j++) acc = fmaf(W0[i*19+3+j], z[b*16+j], acc);
        zc[e] = acc;
    }
    for (int e = tid; e < 4*4096; e += 256){
        W1bf[e] = f2bf(Wres1[e]);
        W2bf[e] = f2bf(Wres2[e]);
    }
}

// ---------------- MFMA residual-MLP decoder + rotate/project ---------------
// 4 waves/block, 16 points/wave. H kept fp32 in D-layout accumulators:
//   lane 16q+c, tile t, reg j  <->  H[row 4q+j][col 16t+c]
// A-frag: lane 16q+p holds X[p][8q..8q+7] (bf16).  B-frag: lane 16q+c holds
//   W[col c][k=8q..8q+7] (bf16, row-major weight rows = B columns).
__launch_bounds__(256, 2)
__global__ void decoder_kernel(const float* __restrict__ pos,
                               const float* __restrict__ W0,
                               const float* __restrict__ scratch,
                               const float* __restrict__ W1a,
                               const float* __restrict__ W1b,
                               float* __restrict__ out_proj_pos,
                               float* __restrict__ out_pos_d,
                               float* __restrict__ out_res,
                               int N)
{
    // 16 rows x 72 bf16 (stride 144B breaks bank collisions), per wave
    __shared__ unsigned short lds[4 * 16 * 72];
    const float* __restrict__ Rm = scratch;
    const float* __restrict__ zc = scratch + 256;
    const unsigned short* __restrict__ W1bf = (const unsigned short*)(scratch + 1280);
    const unsigned short* __restrict__ W2bf = W1bf + 4*4096;

    int b  = blockIdx.y;
    int wv = threadIdx.x >> 6;
    int l  = threadIdx.x & 63;
    int q  = l >> 4, c = l & 15;
    int P0 = blockIdx.x * 64 + wv * 16;
    unsigned short* w_lds = &lds[wv * 16*72];

    // pos for my 4 rows (p = 4q+j), clamped (dup tail rows are never written)
    float pxr[4], pyr[4], pzr[4];
#pragma unroll
    for (int j = 0; j < 4; j++){
        int n = P0 + 4*q + j; if (n > N-1) n = N-1;
        pxr[j] = pos[n*3+0]; pyr[j] = pos[n*3+1]; pzr[j] = pos[n*3+2];
    }

    // H0 = zc[b] + pos @ W0[:, :3]^T   (fp32, D-layout)
    f32x4 H[4];
#pragma unroll
    for (int t = 0; t < 4; t++){
        int i = 16*t + c;
        float w00 = W0[i*19+0], w01 = W0[i*19+1], w02 = W0[i*19+2];
        float zci = zc[b*64 + i];
        f32x4 h;
#pragma unroll
        for (int j = 0; j < 4; j++)
            h[j] = zci + w00*pxr[j] + w01*pyr[j] + w02*pzr[j];
        H[t] = h;
    }

#pragma unroll 1
    for (int ly = 0; ly < 4; ly++){
        const unsigned short* __restrict__ w1l = W1bf + ly*4096;
        const unsigned short* __restrict__ w2l = W2bf + ly*4096;

        // transpose H (bf16) into LDS [row p][col k]
#pragma unroll
        for (int t = 0; t < 4; t++)
#pragma unroll
            for (int j = 0; j < 4; j++)
                w_lds[(4*q+j)*72 + 16*t + c] = f2bf(H[t][j]);

        bf16x8 Ah0 = *(const bf16x8*)&w_lds[(l&15)*72 + 8*q];
        bf16x8 Ah1 = *(const bf16x8*)&w_lds[(l&15)*72 + 32 + 8*q];

        // S = H @ W1^T
        f32x4 S[4];
#pragma unroll
        for (int t = 0; t < 4; t++){
            bf16x8 B0 = *(const bf16x8*)(w1l + (16*t + c)*64 + 8*q);
            bf16x8 B1 = *(const bf16x8*)(w1l + (16*t + c)*64 + 32 + 8*q);
            f32x4 s = {0.f, 0.f, 0.f, 0.f};
            s = __builtin_amdgcn_mfma_f32_16x16x32_bf16(Ah0, B0, s, 0, 0, 0);
            s = __builtin_amdgcn_mfma_f32_16x16x32_bf16(Ah1, B1, s, 0, 0, 0);
            S[t] = s;
        }

        // T = relu(S) -> LDS (bf16, transposed to A-layout)
#pragma unroll
        for (int t = 0; t < 4; t++)
#pragma unroll
            for (int j = 0; j < 4; j++)
                w_lds[(4*q+j)*72 + 16*t + c] = f2bf(fmaxf(S[t][j], 0.f));

        bf16x8 At0 = *(const bf16x8*)&w_lds[(l&15)*72 + 8*q];
        bf16x8 At1 = *(const bf16x8*)&w_lds[(l&15)*72 + 32 + 8*q];

        // H += T @ W2^T  (accumulate straight into the fp32 residual stream)
#pragma unroll
        for (int t = 0; t < 4; t++){
            bf16x8 B0 = *(const bf16x8*)(w2l + (16*t + c)*64 + 8*q);
            bf16x8 B1 = *(const bf16x8*)(w2l + (16*t + c)*64 + 32 + 8*q);
            f32x4 h = H[t];
            h = __builtin_amdgcn_mfma_f32_16x16x32_bf16(At0, B0, h, 0, 0, 0);
            h = __builtin_amdgcn_mfma_f32_16x16x32_bf16(At1, B1, h, 0, 0, 0);
            H[t] = h;
        }
    }

    // epilogue: u = H @ W1a^T (reduce over 64 cols: 4 tiles in-lane + 16-lane butterfly)
    float wa0[4], wa1[4], wa2[4];
#pragma unroll
    for (int t = 0; t < 4; t++){
        wa0[t] = W1a[      16*t + c];
        wa1[t] = W1a[ 64 + 16*t + c];
        wa2[t] = W1a[128 + 16*t + c];
    }
    float myu0 = 0.f, myu1 = 0.f, myu2 = 0.f;
#pragma unroll
    for (int j = 0; j < 4; j++){
        float p0 = 0.f, p1 = 0.f, p2 = 0.f;
#pragma unroll
        for (int t = 0; t < 4; t++){
            p0 = fmaf(H[t][j], wa0[t], p0);
            p1 = fmaf(H[t][j], wa1[t], p1);
            p2 = fmaf(H[t][j], wa2[t], p2);
        }
#pragma unroll
        for (int m = 1; m < 16; m <<= 1){
            p0 += __shfl_xor(p0, m, 64);
            p1 += __shfl_xor(p1, m, 64);
            p2 += __shfl_xor(p2, m, 64);
        }
        if (c == j){ myu0 = p0; myu1 = p1; myu2 = p2; }
    }

    if (c < 4){
        int n = P0 + 4*q + c;
        if (n < N){
            float u0 = tanhf(myu0), u1 = tanhf(myu1), u2 = tanhf(myu2);
            float r0 = u0*W1b[0] + u1*W1b[1] + u2*W1b[2];
            float r1 = u0*W1b[3] + u1*W1b[4] + u2*W1b[5];
            float r2 = u0*W1b[6] + u1*W1b[7] + u2*W1b[8];
            float px = pos[n*3+0], py = pos[n*3+1], pz = pos[n*3+2];
            float pdx = px + r0, pdy = py + r1, pdz = pz + r2;
            const float* Rb = Rm + b*9;
            float q0 = pdx*Rb[0] + pdy*Rb[3] + pdz*Rb[6];
            float q1 = pdx*Rb[1] + pdy*Rb[4] + pdz*Rb[7];
            size_t base = (size_t)b*N + n;
            out_res[base*3+0] = r0;  out_res[base*3+1] = r1;  out_res[base*3+2] = r2;
            out_pos_d[base*3+0] = pdx; out_pos_d[base*3+1] = pdy; out_pos_d[base*3+2] = pdz;
            out_proj_pos[base*2+0] = q0; out_proj_pos[base*2+1] = q1;
        }
    }
}

// ---------------- bilinear splat with LDS privatization --------------------
__launch_bounds__(256)
__global__ void splat_kernel(const float* __restrict__ proj_pos,
                             const float* __restrict__ ampvar,
                             const float* __restrict__ amp,
                             float* __restrict__ proj_im, int N)
{
    __shared__ float tile[2*TS*TS];
    int b = blockIdx.y;
    for (int i = threadIdx.x; i < 2*TS*TS; i += 256) tile[i] = 0.f;
    __syncthreads();

    float ampv = amp[0];
    int n0 = blockIdx.x * NPTS_PER_BLOCK;
    int n1 = min(n0 + NPTS_PER_BLOCK, N);
    for (int n = n0 + (int)threadIdx.x; n < n1; n += 256){
        size_t base = (size_t)b*N + n;
        float cy = proj_pos[base*2+0];
        float cx = proj_pos[base*2+1];
        float e0 = expf(ampvar[n]);
        float e1 = expf(ampvar[N+n]);
        float inv = ampv / (e0 + e1);
        float v0 = e0*inv, v1 = e1*inv;
        float pyf = (cy + 0.5f) * 255.0f;
        float pxf = (cx + 0.5f) * 255.0f;
        float fy0 = floorf(pyf), fx0 = floorf(pxf);
        int iy = (int)fy0, ix = (int)fx0;
        float fy = pyf - fy0, fx = pxf - fx0;
        float wy[2] = {1.f - fy, fy};
        float wx[2] = {1.f - fx, fx};
#pragma unroll
        for (int dy = 0; dy < 2; dy++){
#pragma unroll
            for (int dx = 0; dx < 2; dx++){
                float w = wy[dy]*wx[dx];
                int yi = min(max(iy+dy, 0), 255);
                int xi = min(max(ix+dx, 0), 255);
                int ty = yi - TO, tx = xi - TO;
                if ((unsigned)ty < TS && (unsigned)tx < TS){
                    atomicAdd(&tile[ty*TS + tx],        v0*w);
                    atomicAdd(&tile[TS*TS + ty*TS + tx], v1*w);
                } else {
                    atomicAdd(&proj_im[((size_t)(b*2+0)*256 + yi)*256 + xi], v0*w);
                    atomicAdd(&proj_im[((size_t)(b*2+1)*256 + yi)*256 + xi], v1*w);
                }
            }
        }
    }
    __syncthreads();
    for (int i = threadIdx.x; i < TS*TS; i += 256){
        int ty = i >> 6, tx = i & 63;
        float v = tile[i];
        if (v != 0.f) atomicAdd(&proj_im[((size_t)(b*2+0)*256 + TO+ty)*256 + TO+tx], v);
        v = tile[TS*TS + i];
        if (v != 0.f) atomicAdd(&proj_im[((size_t)(b*2+1)*256 + TO+ty)*256 + TO+tx], v);
    }
}

// ---------------- DFT pass 1: rows, channels packed as complex -------------
__launch_bounds__(256)
__global__ void dft_rows_kernel(const float* __restrict__ proj_im, float2* __restrict__ S)
{
    int b = blockIdx.y, y = blockIdx.x;
    __shared__ float2 row[256];
    int k = threadIdx.x;
    const float* im0 = proj_im + ((size_t)(b*2+0)*256 + y)*256;
    const float* im1 = proj_im + ((size_t)(b*2+1)*256 + y)*256;
    row[k] = make_float2(im0[k], im1[k]);
    __syncthreads();

    float ang = -6.283185307179586f * (float)k / 256.0f;
    float s1,c1,s2,c2,s3,c3,s4,c4;
    sincosf(ang,      &s1, &c1);
    sincosf(2.f*ang,  &s2, &c2);
    sincosf(3.f*ang,  &s3, &c3);
    sincosf(4.f*ang,  &s4, &c4);
    float2 t0 = make_float2(1.f, 0.f), t1 = make_float2(c1, s1);
    float2 t2 = make_float2(c2, s2),   t3 = make_float2(c3, s3);
    float2 tw = make_float2(c4, s4);
    float2 a0 = {0,0}, a1 = {0,0}, a2 = {0,0}, a3 = {0,0};
    for (int x = 0; x < 256; x += 4){
        float2 z0 = row[x], z1 = row[x+1], z2 = row[x+2], z3 = row[x+3];
        cacc(a0, z0, t0); cacc(a1, z1, t1); cacc(a2, z2, t2); cacc(a3, z3, t3);
        t0 = cmul2(t0, tw); t1 = cmul2(t1, tw); t2 = cmul2(t2, tw); t3 = cmul2(t3, tw);
    }
    float2 acc = make_float2(a0.x+a1.x+a2.x+a3.x, a0.y+a1.y+a2.y+a3.y);
    S[((size_t)b*256 + y)*256 + k] = acc;
}

// ---------------- DFT pass 2: columns, IN PLACE ---------------------------
__launch_bounds__(256)
__global__ void dft_cols_kernel(float2* __restrict__ S)
{
    int b = blockIdx.y, kx = blockIdx.x;
    int ky = threadIdx.x;
    __shared__ float2 col[256];
    float2* Sb = S + (size_t)b*65536;
    col[ky] = Sb[(size_t)ky*256 + kx];
    __syncthreads();

    float ang = -6.283185307179586f * (float)ky / 256.0f;
    float s1,c1,s2,c2,s3,c3,s4,c4;
    sincosf(ang,      &s1, &c1);
    sincosf(2.f*ang,  &s2, &c2);
    sincosf(3.f*ang,  &s3, &c3);
    sincosf(4.f*ang,  &s4, &c4);
    float2 t0 = make_float2(1.f, 0.f), t1 = make_float2(c1, s1);
    float2 t2 = make_float2(c2, s2),   t3 = make_float2(c3, s3);
    float2 tw = make_float2(c4, s4);
    float2 a0 = {0,0}, a1 = {0,0}, a2 = {0,0}, a3 = {0,0};
    for (int y = 0; y < 256; y += 4){
        float2 z0 = col[y], z1 = col[y+1], z2 = col[y+2], z3 = col[y+3];
        cacc(a0, z0, t0); cacc(a1, z1, t1); cacc(a2, z2, t2); cacc(a3, z3, t3);
        t0 = cmul2(t0, tw); t1 = cmul2(t1, tw); t2 = cmul2(t2, tw); t3 = cmul2(t3, tw);
    }
    float2 acc = make_float2(a0.x+a1.x+a2.x+a3.x, a0.y+a1.y+a2.y+a3.y);
    Sb[(size_t)ky*256 + kx] = acc;   // Z[b][ky][kx]
}

// ---------------- Hermitian unpack + CTF filter + channel sum --------------
__launch_bounds__(256)
__global__ void combine_kernel(const float2* __restrict__ Z,
                               const float* __restrict__ A, const float* __restrict__ Bc,
                               float* __restrict__ outP, int pairs)
{
    int gid = blockIdx.x*256 + threadIdx.x;
    int b = gid >> 16;
    int lin = gid & 65535;
    int ky = lin >> 8, kx = lin & 255;
    int mky = (256 - ky) & 255, mkx = (256 - kx) & 255;
    int mlin = mky*256 + mkx;
    if (lin > mlin) return;   // pair owner only
    const float2* Zb = Z + (size_t)b*65536;
    float2 Zk = Zb[lin];
    float2 Zm = Zb[mlin];
    float Er = 0.5f*(Zk.x + Zm.x), Ei = 0.5f*(Zk.y - Zm.y);
    float Or = 0.5f*(Zk.y + Zm.y), Oi = 0.5f*(Zm.x - Zk.x);
    float fy = (ky < 128) ? (float)ky : (float)(ky - 256);
    float fx = (kx < 128) ? (float)kx : (float)(kx - 256);
    float rad = rintf(sqrtf(fy*fy + fx*fx));
    float a0 = A[0], a1 = A[1], b0 = Bc[0], b1 = Bc[1];
    float F0 = a0*a0*expf(-b0*b0*rad);
    float F1 = a1*a1*expf(-b1*b1*rad);
    float2 P = make_float2(fmaf(F0, Er, F1*Or), fmaf(F0, Ei, F1*Oi));
    if (pairs){
        float2* O = (float2*)outP + (size_t)b*65536;
        O[lin] = P;
        if (mlin != lin) O[mlin] = make_float2(P.x, -P.y);
    } else {
        float* O = outP + (size_t)b*65536;
        O[lin] = P.x;
        if (mlin != lin) O[mlin] = P.x;
    }
}

extern "C" void kernel_launch(void* const* d_in, const int* in_sizes, int n_in,
                              void* d_out, int out_size, void* d_ws, size_t ws_size,
                              hipStream_t stream)
{
    const float* z      = (const float*)d_in[0];
    const float* r      = (const float*)d_in[1];
    const float* pos    = (const float*)d_in[2];
    const float* amp    = (const float*)d_in[3];
    const float* ampvar = (const float*)d_in[4];
    const float* W0     = (const float*)d_in[5];
    const float* Wres1  = (const float*)d_in[6];
    const float* Wres2  = (const float*)d_in[7];
    const float* W1a    = (const float*)d_in[8];
    const float* W1b    = (const float*)d_in[9];
    const float* A      = (const float*)d_in[10];
    const float* Bc     = (const float*)d_in[11];

    int B = in_sizes[0] / 16;     // 16
    int N = in_sizes[2] / 3;      // 20000

    size_t nIm = (size_t)B * 65536;
    long long tailSz   = (long long)(2*nIm) + 8LL*B*N;
    long long projSize = (long long)out_size - tailSz;
    int pairs = (projSize >= (long long)(2*nIm)) ? 1 : 0;

    float* out = (float*)d_out;
    float* out_proj    = out;
    float* out_projim  = out + projSize;
    float* out_projpos = out_projim + 2*nIm;          // B*N*2
    float* out_posd    = out_projpos + (size_t)B*N*2; // B*N*3
    float* out_res     = out_posd    + (size_t)B*N*3; // B*N*3

    // Scratch (~71KB: Rm, zc, bf16 weights) at the front of the Proj region,
    // which is dead until dft_rows (decoder consumes scratch before that).
    float* scratch = out_proj;

    float2* S;
    if (pairs)                                         S = (float2*)out_proj;
    else if (ws_size >= (size_t)(2*nIm)*sizeof(float)) S = (float2*)d_ws;
    else                                               S = (float2*)out_proj;

    int n4 = (int)(2*nIm/4);
    zero_kernel<<<(n4 + 255)/256, 256, 0, stream>>>((float4*)out_projim, n4);

    setup_kernel<<<1, 256, 0, stream>>>(r, z, W0, Wres1, Wres2, scratch, B);

    dim3 dgrid((N + 63)/64, B);
    decoder_kernel<<<dgrid, 256, 0, stream>>>(pos, W0, scratch, W1a, W1b,
                                              out_projpos, out_posd, out_res, N);

    dim3 sgrid((N + NPTS_PER_BLOCK - 1)/NPTS_PER_BLOCK, B);
    splat_kernel<<<sgrid, 256, 0, stream>>>(out_projpos, ampvar, amp, out_projim, N);

    dim3 fgrid(256, B);
    dft_rows_kernel<<<fgrid, 256, 0, stream>>>(out_projim, S);
    dft_cols_kernel<<<fgrid, 256, 0, stream>>>(S);
    combine_kernel<<<(int)(nIm/256), 256, 0, stream>>>(S, A, Bc, out_proj, pairs);
}

// Round 5
// 222.007 us; speedup vs baseline: 2.1611x; 1.3224x over previous
//
#include <hip/hip_runtime.h>
#include <math.h>

#define NPTS_PER_BLOCK 2048
#define TS 64
#define TO 96

typedef __attribute__((ext_vector_type(8))) short bf16x8;
typedef __attribute__((ext_vector_type(4))) float f32x4;

__device__ __forceinline__ float2 cmul2(float2 a, float2 b){
    return make_float2(fmaf(a.x, b.x, -(a.y*b.y)), fmaf(a.x, b.y, a.y*b.x));
}
__device__ __forceinline__ void cacc(float2& a, float2 z, float2 t){
    a.x = fmaf(z.x, t.x, fmaf(-z.y, t.y, a.x));
    a.y = fmaf(z.x, t.y, fmaf( z.y, t.x, a.y));
}
// float -> bf16 bits, round-nearest-even
__device__ __forceinline__ unsigned short f2bf(float f){
    unsigned u = __float_as_uint(f);
    unsigned r = u + 0x7FFFu + ((u >> 16) & 1u);
    return (unsigned short)(r >> 16);
}

// ---------------- zero a float4-aligned region -----------------------------
__global__ void zero_kernel(float4* __restrict__ p, int n4)
{
    int i = blockIdx.x * blockDim.x + threadIdx.x;
    if (i < n4) p[i] = make_float4(0.f, 0.f, 0.f, 0.f);
}

// ---------------- setup: euler, z-contribution, bf16 weight conversion -----
// scratch (floats): Rm @0 (B*9), zc @256 (B*64), Wbf @1280 (32768 ushorts:
//   W1bf[4][64][64] then W2bf[4][64][64], row-major [layer][out_row][k])
__global__ void setup_kernel(const float* __restrict__ r, const float* __restrict__ z,
                             const float* __restrict__ W0,
                             const float* __restrict__ Wres1,
                             const float* __restrict__ Wres2,
                             float* __restrict__ scratch, int B)
{
    float* Rm  = scratch;
    float* zc  = scratch + 256;
    unsigned short* W1bf = (unsigned short*)(scratch + 1280);
    unsigned short* W2bf = W1bf + 4*4096;
    int tid = threadIdx.x;
    if (tid < B){
        float a = r[tid*3+0], bb = r[tid*3+1], c = r[tid*3+2];
        float ca = cosf(a), sa = sinf(a);
        float cb = cosf(bb), sb = sinf(bb);
        float cc = cosf(c), sc = sinf(c);
        float* Rb = Rm + tid*9;
        Rb[0] = ca*cb*cc - sa*sc;  Rb[1] = -ca*cb*sc - sa*cc;  Rb[2] = ca*sb;
        Rb[3] = sa*cb*cc + ca*sc;  Rb[4] = -sa*cb*sc + ca*cc;  Rb[5] = sa*sb;
        Rb[6] = -sb*cc;            Rb[7] = sb*sc;              Rb[8] = cb;
    }
    for (int e = tid; e < B*64; e += 256){
        int b = e >> 6, i = e & 63;
        float acc = 0.f;
        for (int j = 0; j < 16; j++) acc = fmaf(W0[i*19+3+j], z[b*16+j], acc);
        zc[e] = acc;
    }
    for (int e = tid; e < 4*4096; e += 256){
        W1bf[e] = f2bf(Wres1[e]);
        W2bf[e] = f2bf(Wres2[e]);
    }
}

// ---------------- MFMA residual-MLP decoder + rotate/project ---------------
// 4 waves/block, 64 points/wave (4 M-tiles of 16). H kept fp32 in D-layout:
//   lane 16q+c, M-tile m, N-tile t, reg j <-> H[point 16m+4q+j][col 16t+c]
// A-frag (LDS): lane 16q+c holds A[row 16m+c][k=8q..8q+7]
// B-frag (global weights, row-major [out][k]): lane 16q+c holds W[out c][8q..]
__launch_bounds__(256, 1)
__global__ void decoder_kernel(const float* __restrict__ pos,
                               const float* __restrict__ W0,
                               const float* __restrict__ scratch,
                               const float* __restrict__ W1a,
                               const float* __restrict__ W1b,
                               float* __restrict__ out_proj_pos,
                               float* __restrict__ out_pos_d,
                               float* __restrict__ out_res,
                               int N)
{
    // per wave: 64 rows x 72 bf16 (stride 144B)
    __shared__ unsigned short lds[4 * 64 * 72];
    const float* __restrict__ Rm = scratch;
    const float* __restrict__ zc = scratch + 256;
    const unsigned short* __restrict__ W1bf = (const unsigned short*)(scratch + 1280);
    const unsigned short* __restrict__ W2bf = W1bf + 4*4096;

    int b  = blockIdx.y;
    int wv = threadIdx.x >> 6;
    int l  = threadIdx.x & 63;
    int q  = l >> 4, c = l & 15;
    int P0 = blockIdx.x * 256 + wv * 64;
    unsigned short* w_lds = &lds[wv * 64*72];

    // ---- H0 = zc[b] + pos @ W0[:, :3]^T  (fp32, D-layout) ----
    float zct[4], w0x[4], w0y[4], w0z[4];
#pragma unroll
    for (int t = 0; t < 4; t++){
        int i = 16*t + c;
        zct[t] = zc[b*64 + i];
        w0x[t] = W0[i*19+0]; w0y[t] = W0[i*19+1]; w0z[t] = W0[i*19+2];
    }
    f32x4 H[4][4];   // [m][t]
#pragma unroll
    for (int m = 0; m < 4; m++){
#pragma unroll
        for (int j = 0; j < 4; j++){
            int n = P0 + 16*m + 4*q + j; if (n > N-1) n = N-1;
            float px = pos[n*3+0], py = pos[n*3+1], pz = pos[n*3+2];
#pragma unroll
            for (int t = 0; t < 4; t++)
                H[m][t][j] = zct[t] + w0x[t]*px + w0y[t]*py + w0z[t]*pz;
        }
    }

#pragma unroll 1
    for (int ly = 0; ly < 4; ly++){
        const unsigned short* __restrict__ w1l = W1bf + ly*4096;
        const unsigned short* __restrict__ w2l = W2bf + ly*4096;

        // phase A: H (bf16) -> LDS rows [point][k]
#pragma unroll
        for (int m = 0; m < 4; m++)
#pragma unroll
            for (int t = 0; t < 4; t++)
#pragma unroll
                for (int j = 0; j < 4; j++)
                    w_lds[(16*m + 4*q + j)*72 + 16*t + c] = f2bf(H[m][t][j]);

        // W1 B-frags for this layer (reused across 4 M-tiles)
        bf16x8 W1f0[4], W1f1[4];
#pragma unroll
        for (int t = 0; t < 4; t++){
            W1f0[t] = *(const bf16x8*)(w1l + (16*t + c)*64 + 8*q);
            W1f1[t] = *(const bf16x8*)(w1l + (16*t + c)*64 + 32 + 8*q);
        }

        // phase B: S = H @ W1^T ; relu(S) -> LDS (overwrites rows of m only)
#pragma unroll
        for (int m = 0; m < 4; m++){
            bf16x8 Ah0 = *(const bf16x8*)&w_lds[(16*m + c)*72 + 8*q];
            bf16x8 Ah1 = *(const bf16x8*)&w_lds[(16*m + c)*72 + 32 + 8*q];
            f32x4 S[4];
#pragma unroll
            for (int t = 0; t < 4; t++){
                f32x4 s = {0.f, 0.f, 0.f, 0.f};
                s = __builtin_amdgcn_mfma_f32_16x16x32_bf16(Ah0, W1f0[t], s, 0, 0, 0);
                s = __builtin_amdgcn_mfma_f32_16x16x32_bf16(Ah1, W1f1[t], s, 0, 0, 0);
                S[t] = s;
            }
#pragma unroll
            for (int t = 0; t < 4; t++)
#pragma unroll
                for (int j = 0; j < 4; j++)
                    w_lds[(16*m + 4*q + j)*72 + 16*t + c] = f2bf(fmaxf(S[t][j], 0.f));
        }

        // W2 B-frags
        bf16x8 W2f0[4], W2f1[4];
#pragma unroll
        for (int t = 0; t < 4; t++){
            W2f0[t] = *(const bf16x8*)(w2l + (16*t + c)*64 + 8*q);
            W2f1[t] = *(const bf16x8*)(w2l + (16*t + c)*64 + 32 + 8*q);
        }

        // phase C: H += relu(S) @ W2^T (accumulate into fp32 residual stream)
#pragma unroll
        for (int m = 0; m < 4; m++){
            bf16x8 At0 = *(const bf16x8*)&w_lds[(16*m + c)*72 + 8*q];
            bf16x8 At1 = *(const bf16x8*)&w_lds[(16*m + c)*72 + 32 + 8*q];
#pragma unroll
            for (int t = 0; t < 4; t++){
                f32x4 h = H[m][t];
                h = __builtin_amdgcn_mfma_f32_16x16x32_bf16(At0, W2f0[t], h, 0, 0, 0);
                h = __builtin_amdgcn_mfma_f32_16x16x32_bf16(At1, W2f1[t], h, 0, 0, 0);
                H[m][t] = h;
            }
        }
    }

    // ---- epilogue: u = H @ W1a^T, fp32 butterfly over the 16-lane c-group.
    // Owner lane for (m,j) is c == 4m+j -> every lane owns exactly one point.
    float wa0[4], wa1[4], wa2[4];
#pragma unroll
    for (int t = 0; t < 4; t++){
        wa0[t] = W1a[      16*t + c];
        wa1[t] = W1a[ 64 + 16*t + c];
        wa2[t] = W1a[128 + 16*t + c];
    }
    float myu0 = 0.f, myu1 = 0.f, myu2 = 0.f;
#pragma unroll
    for (int m = 0; m < 4; m++){
#pragma unroll
        for (int j = 0; j < 4; j++){
            float p0 = 0.f, p1 = 0.f, p2 = 0.f;
#pragma unroll
            for (int t = 0; t < 4; t++){
                p0 = fmaf(H[m][t][j], wa0[t], p0);
                p1 = fmaf(H[m][t][j], wa1[t], p1);
                p2 = fmaf(H[m][t][j], wa2[t], p2);
            }
#pragma unroll
            for (int msk = 1; msk < 16; msk <<= 1){
                p0 += __shfl_xor(p0, msk, 64);
                p1 += __shfl_xor(p1, msk, 64);
                p2 += __shfl_xor(p2, msk, 64);
            }
            if (c == 4*m + j){ myu0 = p0; myu1 = p1; myu2 = p2; }
        }
    }

    {
        int n = P0 + 16*(c >> 2) + 4*q + (c & 3);
        if (n < N){
            float u0 = tanhf(myu0), u1 = tanhf(myu1), u2 = tanhf(myu2);
            float r0 = u0*W1b[0] + u1*W1b[1] + u2*W1b[2];
            float r1 = u0*W1b[3] + u1*W1b[4] + u2*W1b[5];
            float r2 = u0*W1b[6] + u1*W1b[7] + u2*W1b[8];
            float px = pos[n*3+0], py = pos[n*3+1], pz = pos[n*3+2];
            float pdx = px + r0, pdy = py + r1, pdz = pz + r2;
            const float* Rb = Rm + b*9;
            float q0 = pdx*Rb[0] + pdy*Rb[3] + pdz*Rb[6];
            float q1 = pdx*Rb[1] + pdy*Rb[4] + pdz*Rb[7];
            size_t base = (size_t)b*N + n;
            out_res[base*3+0] = r0;  out_res[base*3+1] = r1;  out_res[base*3+2] = r2;
            out_pos_d[base*3+0] = pdx; out_pos_d[base*3+1] = pdy; out_pos_d[base*3+2] = pdz;
            out_proj_pos[base*2+0] = q0; out_proj_pos[base*2+1] = q1;
        }
    }
}

// ---------------- bilinear splat with LDS privatization --------------------
__launch_bounds__(256)
__global__ void splat_kernel(const float* __restrict__ proj_pos,
                             const float* __restrict__ ampvar,
                             const float* __restrict__ amp,
                             float* __restrict__ proj_im, int N)
{
    __shared__ float tile[2*TS*TS];
    int b = blockIdx.y;
    for (int i = threadIdx.x; i < 2*TS*TS; i += 256) tile[i] = 0.f;
    __syncthreads();

    float ampv = amp[0];
    int n0 = blockIdx.x * NPTS_PER_BLOCK;
    int n1 = min(n0 + NPTS_PER_BLOCK, N);
    for (int n = n0 + (int)threadIdx.x; n < n1; n += 256){
        size_t base = (size_t)b*N + n;
        float cy = proj_pos[base*2+0];
        float cx = proj_pos[base*2+1];
        float e0 = expf(ampvar[n]);
        float e1 = expf(ampvar[N+n]);
        float inv = ampv / (e0 + e1);
        float v0 = e0*inv, v1 = e1*inv;
        float pyf = (cy + 0.5f) * 255.0f;
        float pxf = (cx + 0.5f) * 255.0f;
        float fy0 = floorf(pyf), fx0 = floorf(pxf);
        int iy = (int)fy0, ix = (int)fx0;
        float fy = pyf - fy0, fx = pxf - fx0;
        float wy[2] = {1.f - fy, fy};
        float wx[2] = {1.f - fx, fx};
#pragma unroll
        for (int dy = 0; dy < 2; dy++){
#pragma unroll
            for (int dx = 0; dx < 2; dx++){
                float w = wy[dy]*wx[dx];
                int yi = min(max(iy+dy, 0), 255);
                int xi = min(max(ix+dx, 0), 255);
                int ty = yi - TO, tx = xi - TO;
                if ((unsigned)ty < TS && (unsigned)tx < TS){
                    atomicAdd(&tile[ty*TS + tx],        v0*w);
                    atomicAdd(&tile[TS*TS + ty*TS + tx], v1*w);
                } else {
                    atomicAdd(&proj_im[((size_t)(b*2+0)*256 + yi)*256 + xi], v0*w);
                    atomicAdd(&proj_im[((size_t)(b*2+1)*256 + yi)*256 + xi], v1*w);
                }
            }
        }
    }
    __syncthreads();
    for (int i = threadIdx.x; i < TS*TS; i += 256){
        int ty = i >> 6, tx = i & 63;
        float v = tile[i];
        if (v != 0.f) atomicAdd(&proj_im[((size_t)(b*2+0)*256 + TO+ty)*256 + TO+tx], v);
        v = tile[TS*TS + i];
        if (v != 0.f) atomicAdd(&proj_im[((size_t)(b*2+1)*256 + TO+ty)*256 + TO+tx], v);
    }
}

// ---------------- DFT pass 1: rows, channels packed as complex -------------
__launch_bounds__(256)
__global__ void dft_rows_kernel(const float* __restrict__ proj_im, float2* __restrict__ S)
{
    int b = blockIdx.y, y = blockIdx.x;
    __shared__ float2 row[256];
    int k = threadIdx.x;
    const float* im0 = proj_im + ((size_t)(b*2+0)*256 + y)*256;
    const float* im1 = proj_im + ((size_t)(b*2+1)*256 + y)*256;
    row[k] = make_float2(im0[k], im1[k]);
    __syncthreads();

    float ang = -6.283185307179586f * (float)k / 256.0f;
    float s1,c1,s2,c2,s3,c3,s4,c4;
    sincosf(ang,      &s1, &c1);
    sincosf(2.f*ang,  &s2, &c2);
    sincosf(3.f*ang,  &s3, &c3);
    sincosf(4.f*ang,  &s4, &c4);
    float2 t0 = make_float2(1.f, 0.f), t1 = make_float2(c1, s1);
    float2 t2 = make_float2(c2, s2),   t3 = make_float2(c3, s3);
    float2 tw = make_float2(c4, s4);
    float2 a0 = {0,0}, a1 = {0,0}, a2 = {0,0}, a3 = {0,0};
    for (int x = 0; x < 256; x += 4){
        float2 z0 = row[x], z1 = row[x+1], z2 = row[x+2], z3 = row[x+3];
        cacc(a0, z0, t0); cacc(a1, z1, t1); cacc(a2, z2, t2); cacc(a3, z3, t3);
        t0 = cmul2(t0, tw); t1 = cmul2(t1, tw); t2 = cmul2(t2, tw); t3 = cmul2(t3, tw);
    }
    float2 acc = make_float2(a0.x+a1.x+a2.x+a3.x, a0.y+a1.y+a2.y+a3.y);
    S[((size_t)b*256 + y)*256 + k] = acc;
}

// ---------------- DFT pass 2: columns, IN PLACE ---------------------------
__launch_bounds__(256)
__global__ void dft_cols_kernel(float2* __restrict__ S)
{
    int b = blockIdx.y, kx = blockIdx.x;
    int ky = threadIdx.x;
    __shared__ float2 col[256];
    float2* Sb = S + (size_t)b*65536;
    col[ky] = Sb[(size_t)ky*256 + kx];
    __syncthreads();

    float ang = -6.283185307179586f * (float)ky / 256.0f;
    float s1,c1,s2,c2,s3,c3,s4,c4;
    sincosf(ang,      &s1, &c1);
    sincosf(2.f*ang,  &s2, &c2);
    sincosf(3.f*ang,  &s3, &c3);
    sincosf(4.f*ang,  &s4, &c4);
    float2 t0 = make_float2(1.f, 0.f), t1 = make_float2(c1, s1);
    float2 t2 = make_float2(c2, s2),   t3 = make_float2(c3, s3);
    float2 tw = make_float2(c4, s4);
    float2 a0 = {0,0}, a1 = {0,0}, a2 = {0,0}, a3 = {0,0};
    for (int y = 0; y < 256; y += 4){
        float2 z0 = col[y], z1 = col[y+1], z2 = col[y+2], z3 = col[y+3];
        cacc(a0, z0, t0); cacc(a1, z1, t1); cacc(a2, z2, t2); cacc(a3, z3, t3);
        t0 = cmul2(t0, tw); t1 = cmul2(t1, tw); t2 = cmul2(t2, tw); t3 = cmul2(t3, tw);
    }
    float2 acc = make_float2(a0.x+a1.x+a2.x+a3.x, a0.y+a1.y+a2.y+a3.y);
    Sb[(size_t)ky*256 + kx] = acc;   // Z[b][ky][kx]
}

// ---------------- Hermitian unpack + CTF filter + channel sum --------------
__launch_bounds__(256)
__global__ void combine_kernel(const float2* __restrict__ Z,
                               const float* __restrict__ A, const float* __restrict__ Bc,
                               float* __restrict__ outP, int pairs)
{
    int gid = blockIdx.x*256 + threadIdx.x;
    int b = gid >> 16;
    int lin = gid & 65535;
    int ky = lin >> 8, kx = lin & 255;
    int mky = (256 - ky) & 255, mkx = (256 - kx) & 255;
    int mlin = mky*256 + mkx;
    if (lin > mlin) return;   // pair owner only
    const float2* Zb = Z + (size_t)b*65536;
    float2 Zk = Zb[lin];
    float2 Zm = Zb[mlin];
    float Er = 0.5f*(Zk.x + Zm.x), Ei = 0.5f*(Zk.y - Zm.y);
    float Or = 0.5f*(Zk.y + Zm.y), Oi = 0.5f*(Zm.x - Zk.x);
    float fy = (ky < 128) ? (float)ky : (float)(ky - 256);
    float fx = (kx < 128) ? (float)kx : (float)(kx - 256);
    float rad = rintf(sqrtf(fy*fy + fx*fx));
    float a0 = A[0], a1 = A[1], b0 = Bc[0], b1 = Bc[1];
    float F0 = a0*a0*expf(-b0*b0*rad);
    float F1 = a1*a1*expf(-b1*b1*rad);
    float2 P = make_float2(fmaf(F0, Er, F1*Or), fmaf(F0, Ei, F1*Oi));
    if (pairs){
        float2* O = (float2*)outP + (size_t)b*65536;
        O[lin] = P;
        if (mlin != lin) O[mlin] = make_float2(P.x, -P.y);
    } else {
        float* O = outP + (size_t)b*65536;
        O[lin] = P.x;
        if (mlin != lin) O[mlin] = P.x;
    }
}

extern "C" void kernel_launch(void* const* d_in, const int* in_sizes, int n_in,
                              void* d_out, int out_size, void* d_ws, size_t ws_size,
                              hipStream_t stream)
{
    const float* z      = (const float*)d_in[0];
    const float* r      = (const float*)d_in[1];
    const float* pos    = (const float*)d_in[2];
    const float* amp    = (const float*)d_in[3];
    const float* ampvar = (const float*)d_in[4];
    const float* W0     = (const float*)d_in[5];
    const float* Wres1  = (const float*)d_in[6];
    const float* Wres2  = (const float*)d_in[7];
    const float* W1a    = (const float*)d_in[8];
    const float* W1b    = (const float*)d_in[9];
    const float* A      = (const float*)d_in[10];
    const float* Bc     = (const float*)d_in[11];

    int B = in_sizes[0] / 16;     // 16
    int N = in_sizes[2] / 3;      // 20000

    size_t nIm = (size_t)B * 65536;
    long long tailSz   = (long long)(2*nIm) + 8LL*B*N;
    long long projSize = (long long)out_size - tailSz;
    int pairs = (projSize >= (long long)(2*nIm)) ? 1 : 0;

    float* out = (float*)d_out;
    float* out_proj    = out;
    float* out_projim  = out + projSize;
    float* out_projpos = out_projim + 2*nIm;          // B*N*2
    float* out_posd    = out_projpos + (size_t)B*N*2; // B*N*3
    float* out_res     = out_posd    + (size_t)B*N*3; // B*N*3

    float* scratch = out_proj;   // dead until dft_rows; decoder consumes first

    float2* S;
    if (pairs)                                         S = (float2*)out_proj;
    else if (ws_size >= (size_t)(2*nIm)*sizeof(float)) S = (float2*)d_ws;
    else                                               S = (float2*)out_proj;

    int n4 = (int)(2*nIm/4);
    zero_kernel<<<(n4 + 255)/256, 256, 0, stream>>>((float4*)out_projim, n4);

    setup_kernel<<<1, 256, 0, stream>>>(r, z, W0, Wres1, Wres2, scratch, B);

    dim3 dgrid((N + 255)/256, B);
    decoder_kernel<<<dgrid, 256, 0, stream>>>(pos, W0, scratch, W1a, W1b,
                                              out_projpos, out_posd, out_res, N);

    dim3 sgrid((N + NPTS_PER_BLOCK - 1)/NPTS_PER_BLOCK, B);
    splat_kernel<<<sgrid, 256, 0, stream>>>(out_projpos, ampvar, amp, out_projim, N);

    dim3 fgrid(256, B);
    dft_rows_kernel<<<fgrid, 256, 0, stream>>>(out_projim, S);
    dft_cols_kernel<<<fgrid, 256, 0, stream>>>(S);
    combine_kernel<<<(int)(nIm/256), 256, 0, stream>>>(S, A, Bc, out_proj, pairs);
}

// Round 6
// 142.547 us; speedup vs baseline: 3.3657x; 1.5574x over previous
//
#include <hip/hip_runtime.h>
#include <math.h>

#define NPTS_PER_BLOCK 2048
#define TS 16
#define TO 120

typedef __attribute__((ext_vector_type(8))) short bf16x8;
typedef __attribute__((ext_vector_type(4))) float f32x4;

__device__ __forceinline__ float2 cmul2(float2 a, float2 b){
    return make_float2(fmaf(a.x, b.x, -(a.y*b.y)), fmaf(a.x, b.y, a.y*b.x));
}
// float -> bf16 bits, round-nearest-even
__device__ __forceinline__ unsigned short f2bf(float f){
    unsigned u = __float_as_uint(f);
    unsigned r = u + 0x7FFFu + ((u >> 16) & 1u);
    return (unsigned short)(r >> 16);
}
// swizzled byte offset within a 64-row x 128B LDS tile: chunk ^= row&7
__device__ __forceinline__ int swz(int row, int byteInRow){
    return row*128 + ((((byteInRow >> 4) ^ row) & 7) << 4) + (byteInRow & 15);
}

// ---------------- zero a float4-aligned region -----------------------------
__global__ void zero_kernel(float4* __restrict__ p, int n4)
{
    int i = blockIdx.x * blockDim.x + threadIdx.x;
    if (i < n4) p[i] = make_float4(0.f, 0.f, 0.f, 0.f);
}

// ---------------- setup: euler, z-contribution, permuted bf16 weights ------
// scratch (floats): Rm @0 (B*9), zc @256 (B*64), Wbf @1280 (32768 ushorts)
// Weights stored k'-PERMUTED: Wp[out][k'] = W[out][16*(k'&3) + (k'>>2)]
__global__ void setup_kernel(const float* __restrict__ r, const float* __restrict__ z,
                             const float* __restrict__ W0,
                             const float* __restrict__ Wres1,
                             const float* __restrict__ Wres2,
                             float* __restrict__ scratch, int B)
{
    float* Rm  = scratch;
    float* zc  = scratch + 256;
    unsigned short* W1bf = (unsigned short*)(scratch + 1280);
    unsigned short* W2bf = W1bf + 4*4096;
    int tid = threadIdx.x;
    if (tid < B){
        float a = r[tid*3+0], bb = r[tid*3+1], c = r[tid*3+2];
        float ca = cosf(a), sa = sinf(a);
        float cb = cosf(bb), sb = sinf(bb);
        float cc = cosf(c), sc = sinf(c);
        float* Rb = Rm + tid*9;
        Rb[0] = ca*cb*cc - sa*sc;  Rb[1] = -ca*cb*sc - sa*cc;  Rb[2] = ca*sb;
        Rb[3] = sa*cb*cc + ca*sc;  Rb[4] = -sa*cb*sc + ca*cc;  Rb[5] = sa*sb;
        Rb[6] = -sb*cc;            Rb[7] = sb*sc;              Rb[8] = cb;
    }
    for (int e = tid; e < B*64; e += 256){
        int b = e >> 6, i = e & 63;
        float acc = 0.f;
        for (int j = 0; j < 16; j++) acc = fmaf(W0[i*19+3+j], z[b*16+j], acc);
        zc[e] = acc;
    }
    for (int e = tid; e < 4*4096; e += 256){
        int l = e >> 12, rem = e & 4095, orow = rem >> 6, kp = rem & 63;
        int k = 16*(kp & 3) + (kp >> 2);
        int src = l*4096 + orow*64 + k;
        W1bf[e] = f2bf(Wres1[src]);
        W2bf[e] = f2bf(Wres2[src]);
    }
}

// ---------------- MFMA residual-MLP decoder + rotate/project ---------------
// 4 waves/block, 64 points/wave. H fp32 in D-layout:
//   lane 16q+c, M-tile m, N-tile t, reg j <-> H[point 16m+4q+j][feat 16t+c]
// LDS transpose uses k' = 4c+t ordering (weights pre-permuted to match) and
// XOR chunk swizzle -> b64 writes / b128 reads, both bank-optimal.
__launch_bounds__(256, 1)
__global__ void decoder_kernel(const float* __restrict__ pos,
                               const float* __restrict__ W0,
                               const float* __restrict__ scratch,
                               const float* __restrict__ W1a,
                               const float* __restrict__ W1b,
                               float* __restrict__ out_proj_pos,
                               float* __restrict__ out_pos_d,
                               float* __restrict__ out_res,
                               int N)
{
    __shared__ unsigned short lds[4 * 64 * 64];   // 4 waves x (64 rows x 128B)
    const float* __restrict__ Rm = scratch;
    const float* __restrict__ zc = scratch + 256;
    const unsigned short* __restrict__ W1bf = (const unsigned short*)(scratch + 1280);
    const unsigned short* __restrict__ W2bf = W1bf + 4*4096;

    int b  = blockIdx.y;
    int wv = threadIdx.x >> 6;
    int l  = threadIdx.x & 63;
    int q  = l >> 4, c = l & 15;
    int P0 = blockIdx.x * 256 + wv * 64;
    char* ldsb = (char*)&lds[wv * 64 * 64];

    // ---- H0 = zc[b] + pos @ W0[:, :3]^T  (fp32, D-layout) ----
    float zct[4], w0x[4], w0y[4], w0z[4];
#pragma unroll
    for (int t = 0; t < 4; t++){
        int i = 16*t + c;
        zct[t] = zc[b*64 + i];
        w0x[t] = W0[i*19+0]; w0y[t] = W0[i*19+1]; w0z[t] = W0[i*19+2];
    }
    f32x4 H[4][4];   // [m][t]
    bool fast = (P0 + 64 <= N);
#pragma unroll
    for (int m = 0; m < 4; m++){
        float px[4], py[4], pz[4];
        if (fast){
            const float4* pp = (const float4*)(pos + 3*(P0 + 16*m + 4*q));
            float4 A0 = pp[0], A1 = pp[1], A2 = pp[2];
            px[0]=A0.x; py[0]=A0.y; pz[0]=A0.z;
            px[1]=A0.w; py[1]=A1.x; pz[1]=A1.y;
            px[2]=A1.z; py[2]=A1.w; pz[2]=A2.x;
            px[3]=A2.y; py[3]=A2.z; pz[3]=A2.w;
        } else {
#pragma unroll
            for (int j = 0; j < 4; j++){
                int n = P0 + 16*m + 4*q + j; if (n > N-1) n = N-1;
                px[j] = pos[n*3+0]; py[j] = pos[n*3+1]; pz[j] = pos[n*3+2];
            }
        }
#pragma unroll
        for (int j = 0; j < 4; j++)
#pragma unroll
            for (int t = 0; t < 4; t++)
                H[m][t][j] = zct[t] + w0x[t]*px[j] + w0y[t]*py[j] + w0z[t]*pz[j];
    }

#pragma unroll 1
    for (int ly = 0; ly < 4; ly++){
        const unsigned short* __restrict__ w1l = W1bf + ly*4096;
        const unsigned short* __restrict__ w2l = W2bf + ly*4096;

        // phase A: H -> LDS, packed b64 (4 t-values at k' = 4c..4c+3)
#pragma unroll
        for (int m = 0; m < 4; m++)
#pragma unroll
            for (int j = 0; j < 4; j++){
                ushort4 v;
                v.x = f2bf(H[m][0][j]); v.y = f2bf(H[m][1][j]);
                v.z = f2bf(H[m][2][j]); v.w = f2bf(H[m][3][j]);
                *(ushort4*)(ldsb + swz(16*m + 4*q + j, 8*c)) = v;
            }

        // W1 B-frags (permuted layout, reused across 4 M-tiles)
        bf16x8 W1f0[4], W1f1[4];
#pragma unroll
        for (int t = 0; t < 4; t++){
            W1f0[t] = *(const bf16x8*)(w1l + (16*t + c)*64 + 8*q);
            W1f1[t] = *(const bf16x8*)(w1l + (16*t + c)*64 + 32 + 8*q);
        }

        // phase B: S = H @ W1^T ; relu -> LDS (packed b64)
#pragma unroll
        for (int m = 0; m < 4; m++){
            bf16x8 Ah0 = *(const bf16x8*)(ldsb + swz(16*m + c, 16*q));
            bf16x8 Ah1 = *(const bf16x8*)(ldsb + swz(16*m + c, 64 + 16*q));
            f32x4 S[4];
#pragma unroll
            for (int t = 0; t < 4; t++){
                f32x4 s = {0.f, 0.f, 0.f, 0.f};
                s = __builtin_amdgcn_mfma_f32_16x16x32_bf16(Ah0, W1f0[t], s, 0, 0, 0);
                s = __builtin_amdgcn_mfma_f32_16x16x32_bf16(Ah1, W1f1[t], s, 0, 0, 0);
                S[t] = s;
            }
#pragma unroll
            for (int j = 0; j < 4; j++){
                ushort4 v;
                v.x = f2bf(fmaxf(S[0][j], 0.f)); v.y = f2bf(fmaxf(S[1][j], 0.f));
                v.z = f2bf(fmaxf(S[2][j], 0.f)); v.w = f2bf(fmaxf(S[3][j], 0.f));
                *(ushort4*)(ldsb + swz(16*m + 4*q + j, 8*c)) = v;
            }
        }

        // W2 B-frags
        bf16x8 W2f0[4], W2f1[4];
#pragma unroll
        for (int t = 0; t < 4; t++){
            W2f0[t] = *(const bf16x8*)(w2l + (16*t + c)*64 + 8*q);
            W2f1[t] = *(const bf16x8*)(w2l + (16*t + c)*64 + 32 + 8*q);
        }

        // phase C: H += relu(S) @ W2^T
#pragma unroll
        for (int m = 0; m < 4; m++){
            bf16x8 At0 = *(const bf16x8*)(ldsb + swz(16*m + c, 16*q));
            bf16x8 At1 = *(const bf16x8*)(ldsb + swz(16*m + c, 64 + 16*q));
#pragma unroll
            for (int t = 0; t < 4; t++){
                f32x4 h = H[m][t];
                h = __builtin_amdgcn_mfma_f32_16x16x32_bf16(At0, W2f0[t], h, 0, 0, 0);
                h = __builtin_amdgcn_mfma_f32_16x16x32_bf16(At1, W2f1[t], h, 0, 0, 0);
                H[m][t] = h;
            }
        }
    }

    // ---- epilogue: u = H @ W1a^T; butterfly over 16-lane c-groups ----
    float wa0[4], wa1[4], wa2[4];
#pragma unroll
    for (int t = 0; t < 4; t++){
        wa0[t] = W1a[      16*t + c];
        wa1[t] = W1a[ 64 + 16*t + c];
        wa2[t] = W1a[128 + 16*t + c];
    }
    float myu0 = 0.f, myu1 = 0.f, myu2 = 0.f;
#pragma unroll
    for (int m = 0; m < 4; m++){
#pragma unroll
        for (int j = 0; j < 4; j++){
            float p0 = 0.f, p1 = 0.f, p2 = 0.f;
#pragma unroll
            for (int t = 0; t < 4; t++){
                p0 = fmaf(H[m][t][j], wa0[t], p0);
                p1 = fmaf(H[m][t][j], wa1[t], p1);
                p2 = fmaf(H[m][t][j], wa2[t], p2);
            }
#pragma unroll
            for (int msk = 1; msk < 16; msk <<= 1){
                p0 += __shfl_xor(p0, msk, 64);
                p1 += __shfl_xor(p1, msk, 64);
                p2 += __shfl_xor(p2, msk, 64);
            }
            if (c == 4*m + j){ myu0 = p0; myu1 = p1; myu2 = p2; }
        }
    }
    {
        int n = P0 + 16*(c >> 2) + 4*q + (c & 3);
        if (n < N){
            float u0 = tanhf(myu0), u1 = tanhf(myu1), u2 = tanhf(myu2);
            float r0 = u0*W1b[0] + u1*W1b[1] + u2*W1b[2];
            float r1 = u0*W1b[3] + u1*W1b[4] + u2*W1b[5];
            float r2 = u0*W1b[6] + u1*W1b[7] + u2*W1b[8];
            float px = pos[n*3+0], py = pos[n*3+1], pz = pos[n*3+2];
            float pdx = px + r0, pdy = py + r1, pdz = pz + r2;
            const float* Rb = Rm + b*9;
            float q0 = pdx*Rb[0] + pdy*Rb[3] + pdz*Rb[6];
            float q1 = pdx*Rb[1] + pdy*Rb[4] + pdz*Rb[7];
            size_t base = (size_t)b*N + n;
            out_res[base*3+0] = r0;  out_res[base*3+1] = r1;  out_res[base*3+2] = r2;
            out_pos_d[base*3+0] = pdx; out_pos_d[base*3+1] = pdy; out_pos_d[base*3+2] = pdz;
            out_proj_pos[base*2+0] = q0; out_proj_pos[base*2+1] = q1;
        }
    }
}

// ---------------- bilinear splat with LDS privatization --------------------
__launch_bounds__(256)
__global__ void splat_kernel(const float* __restrict__ proj_pos,
                             const float* __restrict__ ampvar,
                             const float* __restrict__ amp,
                             float* __restrict__ proj_im, int N)
{
    __shared__ float tile[2*TS*TS];
    int b = blockIdx.y;
    for (int i = threadIdx.x; i < 2*TS*TS; i += 256) tile[i] = 0.f;
    __syncthreads();

    float ampv = amp[0];
    int n0 = blockIdx.x * NPTS_PER_BLOCK;
    int n1 = min(n0 + NPTS_PER_BLOCK, N);
    for (int n = n0 + (int)threadIdx.x; n < n1; n += 256){
        size_t base = (size_t)b*N + n;
        float cy = proj_pos[base*2+0];
        float cx = proj_pos[base*2+1];
        float e0 = expf(ampvar[n]);
        float e1 = expf(ampvar[N+n]);
        float inv = ampv / (e0 + e1);
        float v0 = e0*inv, v1 = e1*inv;
        float pyf = (cy + 0.5f) * 255.0f;
        float pxf = (cx + 0.5f) * 255.0f;
        float fy0 = floorf(pyf), fx0 = floorf(pxf);
        int iy = (int)fy0, ix = (int)fx0;
        float fy = pyf - fy0, fx = pxf - fx0;
        float wy[2] = {1.f - fy, fy};
        float wx[2] = {1.f - fx, fx};
#pragma unroll
        for (int dy = 0; dy < 2; dy++){
#pragma unroll
            for (int dx = 0; dx < 2; dx++){
                float w = wy[dy]*wx[dx];
                int yi = min(max(iy+dy, 0), 255);
                int xi = min(max(ix+dx, 0), 255);
                int ty = yi - TO, tx = xi - TO;
                if ((unsigned)ty < TS && (unsigned)tx < TS){
                    atomicAdd(&tile[ty*TS + tx],        v0*w);
                    atomicAdd(&tile[TS*TS + ty*TS + tx], v1*w);
                } else {
                    atomicAdd(&proj_im[((size_t)(b*2+0)*256 + yi)*256 + xi], v0*w);
                    atomicAdd(&proj_im[((size_t)(b*2+1)*256 + yi)*256 + xi], v1*w);
                }
            }
        }
    }
    __syncthreads();
    for (int i = threadIdx.x; i < TS*TS; i += 256){
        int ty = i >> 4, tx = i & (TS-1);
        float v = tile[i];
        if (v != 0.f) atomicAdd(&proj_im[((size_t)(b*2+0)*256 + TO+ty)*256 + TO+tx], v);
        v = tile[TS*TS + i];
        if (v != 0.f) atomicAdd(&proj_im[((size_t)(b*2+1)*256 + TO+ty)*256 + TO+tx], v);
    }
}

// ---------------- DFT pass 1: rows, sparse-aware (nonzero bitmask) ---------
__launch_bounds__(256)
__global__ void dft_rows_kernel(const float* __restrict__ proj_im, float2* __restrict__ S)
{
    int b = blockIdx.y, y = blockIdx.x;
    __shared__ float2 row[256];
    __shared__ unsigned long long nzm[4];
    int k = threadIdx.x;
    const float* im0 = proj_im + ((size_t)(b*2+0)*256 + y)*256;
    const float* im1 = proj_im + ((size_t)(b*2+1)*256 + y)*256;
    float2 my = make_float2(im0[k], im1[k]);
    row[k] = my;
    unsigned long long bal = __ballot(my.x != 0.f || my.y != 0.f);
    if ((k & 63) == 0) nzm[k >> 6] = bal;
    __syncthreads();

    const float w = -6.283185307179586f / 256.0f;
    float2 acc = make_float2(0.f, 0.f);
#pragma unroll 1
    for (int g = 0; g < 4; g++){
        unsigned long long mm = nzm[g];
        while (mm){
            int x = (g << 6) + __ffsll((long long)mm) - 1;
            mm &= mm - 1;
            float2 zv = row[x];
            float s, c;
            sincosf(w * (float)((k * x) & 255), &s, &c);
            acc.x = fmaf(zv.x, c, fmaf(-zv.y, s, acc.x));
            acc.y = fmaf(zv.x, s, fmaf( zv.y, c, acc.y));
        }
    }
    S[((size_t)b*256 + y)*256 + k] = acc;
}

// ---------------- DFT pass 2: columns, IN PLACE, sparse-aware --------------
__launch_bounds__(256)
__global__ void dft_cols_kernel(float2* __restrict__ S)
{
    int b = blockIdx.y, kx = blockIdx.x;
    int ky = threadIdx.x;
    __shared__ float2 col[256];
    __shared__ unsigned long long nzm[4];
    float2* Sb = S + (size_t)b*65536;
    float2 my = Sb[(size_t)ky*256 + kx];
    col[ky] = my;
    unsigned long long bal = __ballot(my.x != 0.f || my.y != 0.f);
    if ((ky & 63) == 0) nzm[ky >> 6] = bal;
    __syncthreads();

    const float w = -6.283185307179586f / 256.0f;
    float2 acc = make_float2(0.f, 0.f);
#pragma unroll 1
    for (int g = 0; g < 4; g++){
        unsigned long long mm = nzm[g];
        while (mm){
            int y = (g << 6) + __ffsll((long long)mm) - 1;
            mm &= mm - 1;
            float2 zv = col[y];
            float s, c;
            sincosf(w * (float)((ky * y) & 255), &s, &c);
            acc.x = fmaf(zv.x, c, fmaf(-zv.y, s, acc.x));
            acc.y = fmaf(zv.x, s, fmaf( zv.y, c, acc.y));
        }
    }
    Sb[(size_t)ky*256 + kx] = acc;   // Z[b][ky][kx]
}

// ---------------- Hermitian unpack + CTF filter + channel sum --------------
__launch_bounds__(256)
__global__ void combine_kernel(const float2* __restrict__ Z,
                               const float* __restrict__ A, const float* __restrict__ Bc,
                               float* __restrict__ outP, int pairs)
{
    int gid = blockIdx.x*256 + threadIdx.x;
    int b = gid >> 16;
    int lin = gid & 65535;
    int ky = lin >> 8, kx = lin & 255;
    int mky = (256 - ky) & 255, mkx = (256 - kx) & 255;
    int mlin = mky*256 + mkx;
    if (lin > mlin) return;   // pair owner only
    const float2* Zb = Z + (size_t)b*65536;
    float2 Zk = Zb[lin];
    float2 Zm = Zb[mlin];
    float Er = 0.5f*(Zk.x + Zm.x), Ei = 0.5f*(Zk.y - Zm.y);
    float Or = 0.5f*(Zk.y + Zm.y), Oi = 0.5f*(Zm.x - Zk.x);
    float fy = (ky < 128) ? (float)ky : (float)(ky - 256);
    float fx = (kx < 128) ? (float)kx : (float)(kx - 256);
    float rad = rintf(sqrtf(fy*fy + fx*fx));
    float a0 = A[0], a1 = A[1], b0 = Bc[0], b1 = Bc[1];
    float F0 = a0*a0*expf(-b0*b0*rad);
    float F1 = a1*a1*expf(-b1*b1*rad);
    float2 P = make_float2(fmaf(F0, Er, F1*Or), fmaf(F0, Ei, F1*Oi));
    if (pairs){
        float2* O = (float2*)outP + (size_t)b*65536;
        O[lin] = P;
        if (mlin != lin) O[mlin] = make_float2(P.x, -P.y);
    } else {
        float* O = outP + (size_t)b*65536;
        O[lin] = P.x;
        if (mlin != lin) O[mlin] = P.x;
    }
}

extern "C" void kernel_launch(void* const* d_in, const int* in_sizes, int n_in,
                              void* d_out, int out_size, void* d_ws, size_t ws_size,
                              hipStream_t stream)
{
    const float* z      = (const float*)d_in[0];
    const float* r      = (const float*)d_in[1];
    const float* pos    = (const float*)d_in[2];
    const float* amp    = (const float*)d_in[3];
    const float* ampvar = (const float*)d_in[4];
    const float* W0     = (const float*)d_in[5];
    const float* Wres1  = (const float*)d_in[6];
    const float* Wres2  = (const float*)d_in[7];
    const float* W1a    = (const float*)d_in[8];
    const float* W1b    = (const float*)d_in[9];
    const float* A      = (const float*)d_in[10];
    const float* Bc     = (const float*)d_in[11];

    int B = in_sizes[0] / 16;     // 16
    int N = in_sizes[2] / 3;      // 20000

    size_t nIm = (size_t)B * 65536;
    long long tailSz   = (long long)(2*nIm) + 8LL*B*N;
    long long projSize = (long long)out_size - tailSz;
    int pairs = (projSize >= (long long)(2*nIm)) ? 1 : 0;

    float* out = (float*)d_out;
    float* out_proj    = out;
    float* out_projim  = out + projSize;
    float* out_projpos = out_projim + 2*nIm;          // B*N*2
    float* out_posd    = out_projpos + (size_t)B*N*2; // B*N*3
    float* out_res     = out_posd    + (size_t)B*N*3; // B*N*3

    float* scratch = out_proj;   // dead until dft_rows; decoder consumes first

    float2* S;
    if (pairs)                                         S = (float2*)out_proj;
    else if (ws_size >= (size_t)(2*nIm)*sizeof(float)) S = (float2*)d_ws;
    else                                               S = (float2*)out_proj;

    int n4 = (int)(2*nIm/4);
    zero_kernel<<<(n4 + 255)/256, 256, 0, stream>>>((float4*)out_projim, n4);

    setup_kernel<<<1, 256, 0, stream>>>(r, z, W0, Wres1, Wres2, scratch, B);

    dim3 dgrid((N + 255)/256, B);
    decoder_kernel<<<dgrid, 256, 0, stream>>>(pos, W0, scratch, W1a, W1b,
                                              out_projpos, out_posd, out_res, N);

    dim3 sgrid((N + NPTS_PER_BLOCK - 1)/NPTS_PER_BLOCK, B);
    splat_kernel<<<sgrid, 256, 0, stream>>>(out_projpos, ampvar, amp, out_projim, N);

    dim3 fgrid(256, B);
    dft_rows_kernel<<<fgrid, 256, 0, stream>>>(out_projim, S);
    dft_cols_kernel<<<fgrid, 256, 0, stream>>>(S);
    combine_kernel<<<(int)(nIm/256), 256, 0, stream>>>(S, A, Bc, out_proj, pairs);
}

// Round 7
// 117.503 us; speedup vs baseline: 4.0831x; 1.2131x over previous
//
#include <hip/hip_runtime.h>
#include <math.h>

#define NPTS_PER_BLOCK 2048
#define TS 16
#define TO 120
#define KXT 16

typedef __attribute__((ext_vector_type(8))) short bf16x8;
typedef __attribute__((ext_vector_type(4))) float f32x4;

// float -> bf16 bits, round-nearest-even (software; setup only)
__device__ __forceinline__ unsigned short f2bf(float f){
    unsigned u = __float_as_uint(f);
    unsigned r = u + 0x7FFFu + ((u >> 16) & 1u);
    return (unsigned short)(r >> 16);
}
// HW packed f32x2 -> bf16x2 (RNE), gfx950
__device__ __forceinline__ unsigned pk_bf16(float lo, float hi){
    unsigned d;
    asm("v_cvt_pk_bf16_f32 %0, %1, %2" : "=v"(d) : "v"(lo), "v"(hi));
    return d;
}
// swizzled byte offset within a 64-row x 128B LDS tile: chunk ^= row&7
__device__ __forceinline__ int swz(int row, int byteInRow){
    return row*128 + ((((byteInRow >> 4) ^ row) & 7) << 4) + (byteInRow & 15);
}

// ---------------- zero a float4-aligned region -----------------------------
__global__ void zero_kernel(float4* __restrict__ p, int n4)
{
    int i = blockIdx.x * blockDim.x + threadIdx.x;
    if (i < n4) p[i] = make_float4(0.f, 0.f, 0.f, 0.f);
}

// ---------------- setup: euler, z-contribution, permuted bf16 weights ------
// scratch (floats): Rm @0 (B*9), zc @256 (B*64), Wbf @1280 (32768 ushorts)
// Weights stored k'-PERMUTED: Wp[out][k'] = W[out][16*(k'&3) + (k'>>2)]
// grid: 17 blocks. Block 0: Rm+zc. Blocks 1..16: 1024 weight entries each.
__global__ void setup_kernel(const float* __restrict__ r, const float* __restrict__ z,
                             const float* __restrict__ W0,
                             const float* __restrict__ Wres1,
                             const float* __restrict__ Wres2,
                             float* __restrict__ scratch, int B)
{
    float* Rm  = scratch;
    float* zc  = scratch + 256;
    unsigned short* W1bf = (unsigned short*)(scratch + 1280);
    unsigned short* W2bf = W1bf + 4*4096;
    int blk = blockIdx.x, tid = threadIdx.x;
    if (blk == 0){
        if (tid < B){
            float a = r[tid*3+0], bb = r[tid*3+1], c = r[tid*3+2];
            float ca = cosf(a), sa = sinf(a);
            float cb = cosf(bb), sb = sinf(bb);
            float cc = cosf(c), sc = sinf(c);
            float* Rb = Rm + tid*9;
            Rb[0] = ca*cb*cc - sa*sc;  Rb[1] = -ca*cb*sc - sa*cc;  Rb[2] = ca*sb;
            Rb[3] = sa*cb*cc + ca*sc;  Rb[4] = -sa*cb*sc + ca*cc;  Rb[5] = sa*sb;
            Rb[6] = -sb*cc;            Rb[7] = sb*sc;              Rb[8] = cb;
        }
        for (int e = tid; e < B*64; e += 256){
            int b = e >> 6, i = e & 63;
            float acc = 0.f;
            for (int j = 0; j < 16; j++) acc = fmaf(W0[i*19+3+j], z[b*16+j], acc);
            zc[e] = acc;
        }
    } else {
        int base = (blk - 1) * 1024;
        for (int e = base + tid; e < base + 1024; e += 256){
            int l = e >> 12, rem = e & 4095, orow = rem >> 6, kp = rem & 63;
            int k = 16*(kp & 3) + (kp >> 2);
            int src = l*4096 + orow*64 + k;
            W1bf[e] = f2bf(Wres1[src]);
            W2bf[e] = f2bf(Wres2[src]);
        }
    }
}

// ---------------- MFMA residual-MLP decoder + rotate/project ---------------
// 4 waves/block, 64 points/wave. H fp32 in D-layout:
//   lane 16q+c, M-tile m, N-tile t, reg j <-> H[point 16m+4q+j][feat 16t+c]
// LDS transpose uses k' = 4c+t ordering (weights pre-permuted to match) and
// XOR chunk swizzle -> b64 writes / b128 reads, both bank-optimal.
__launch_bounds__(256, 1)
__global__ void decoder_kernel(const float* __restrict__ pos,
                               const float* __restrict__ W0,
                               const float* __restrict__ scratch,
                               const float* __restrict__ W1a,
                               const float* __restrict__ W1b,
                               float* __restrict__ out_proj_pos,
                               float* __restrict__ out_pos_d,
                               float* __restrict__ out_res,
                               int N)
{
    __shared__ unsigned short lds[4 * 64 * 64];   // 4 waves x (64 rows x 128B)
    const float* __restrict__ Rm = scratch;
    const float* __restrict__ zc = scratch + 256;
    const unsigned short* __restrict__ W1bf = (const unsigned short*)(scratch + 1280);
    const unsigned short* __restrict__ W2bf = W1bf + 4*4096;

    int b  = blockIdx.y;
    int wv = threadIdx.x >> 6;
    int l  = threadIdx.x & 63;
    int q  = l >> 4, c = l & 15;
    int P0 = blockIdx.x * 256 + wv * 64;
    char* ldsb = (char*)&lds[wv * 64 * 64];

    // ---- H0 = zc[b] + pos @ W0[:, :3]^T  (fp32, D-layout) ----
    float zct[4], w0x[4], w0y[4], w0z[4];
#pragma unroll
    for (int t = 0; t < 4; t++){
        int i = 16*t + c;
        zct[t] = zc[b*64 + i];
        w0x[t] = W0[i*19+0]; w0y[t] = W0[i*19+1]; w0z[t] = W0[i*19+2];
    }
    f32x4 H[4][4];   // [m][t]
    bool fast = (P0 + 64 <= N);
#pragma unroll
    for (int m = 0; m < 4; m++){
        float px[4], py[4], pz[4];
        if (fast){
            const float4* pp = (const float4*)(pos + 3*(P0 + 16*m + 4*q));
            float4 A0 = pp[0], A1 = pp[1], A2 = pp[2];
            px[0]=A0.x; py[0]=A0.y; pz[0]=A0.z;
            px[1]=A0.w; py[1]=A1.x; pz[1]=A1.y;
            px[2]=A1.z; py[2]=A1.w; pz[2]=A2.x;
            px[3]=A2.y; py[3]=A2.z; pz[3]=A2.w;
        } else {
#pragma unroll
            for (int j = 0; j < 4; j++){
                int n = P0 + 16*m + 4*q + j; if (n > N-1) n = N-1;
                px[j] = pos[n*3+0]; py[j] = pos[n*3+1]; pz[j] = pos[n*3+2];
            }
        }
#pragma unroll
        for (int j = 0; j < 4; j++)
#pragma unroll
            for (int t = 0; t < 4; t++)
                H[m][t][j] = zct[t] + w0x[t]*px[j] + w0y[t]*py[j] + w0z[t]*pz[j];
    }

#pragma unroll 1
    for (int ly = 0; ly < 4; ly++){
        const unsigned short* __restrict__ w1l = W1bf + ly*4096;
        const unsigned short* __restrict__ w2l = W2bf + ly*4096;

        // phase A: H -> LDS, packed b64 (4 t-values at k' = 4c..4c+3)
#pragma unroll
        for (int m = 0; m < 4; m++)
#pragma unroll
            for (int j = 0; j < 4; j++){
                uint2 v;
                v.x = pk_bf16(H[m][0][j], H[m][1][j]);
                v.y = pk_bf16(H[m][2][j], H[m][3][j]);
                *(uint2*)(ldsb + swz(16*m + 4*q + j, 8*c)) = v;
            }

        // W1 B-frags (permuted layout, reused across 4 M-tiles)
        bf16x8 W1f0[4], W1f1[4];
#pragma unroll
        for (int t = 0; t < 4; t++){
            W1f0[t] = *(const bf16x8*)(w1l + (16*t + c)*64 + 8*q);
            W1f1[t] = *(const bf16x8*)(w1l + (16*t + c)*64 + 32 + 8*q);
        }

        // phase B: S = H @ W1^T ; relu -> LDS (packed b64)
#pragma unroll
        for (int m = 0; m < 4; m++){
            bf16x8 Ah0 = *(const bf16x8*)(ldsb + swz(16*m + c, 16*q));
            bf16x8 Ah1 = *(const bf16x8*)(ldsb + swz(16*m + c, 64 + 16*q));
            f32x4 S[4];
#pragma unroll
            for (int t = 0; t < 4; t++){
                f32x4 s = {0.f, 0.f, 0.f, 0.f};
                s = __builtin_amdgcn_mfma_f32_16x16x32_bf16(Ah0, W1f0[t], s, 0, 0, 0);
                s = __builtin_amdgcn_mfma_f32_16x16x32_bf16(Ah1, W1f1[t], s, 0, 0, 0);
                S[t] = s;
            }
#pragma unroll
            for (int j = 0; j < 4; j++){
                uint2 v;
                v.x = pk_bf16(fmaxf(S[0][j], 0.f), fmaxf(S[1][j], 0.f));
                v.y = pk_bf16(fmaxf(S[2][j], 0.f), fmaxf(S[3][j], 0.f));
                *(uint2*)(ldsb + swz(16*m + 4*q + j, 8*c)) = v;
            }
        }

        // W2 B-frags
        bf16x8 W2f0[4], W2f1[4];
#pragma unroll
        for (int t = 0; t < 4; t++){
            W2f0[t] = *(const bf16x8*)(w2l + (16*t + c)*64 + 8*q);
            W2f1[t] = *(const bf16x8*)(w2l + (16*t + c)*64 + 32 + 8*q);
        }

        // phase C: H += relu(S) @ W2^T
#pragma unroll
        for (int m = 0; m < 4; m++){
            bf16x8 At0 = *(const bf16x8*)(ldsb + swz(16*m + c, 16*q));
            bf16x8 At1 = *(const bf16x8*)(ldsb + swz(16*m + c, 64 + 16*q));
#pragma unroll
            for (int t = 0; t < 4; t++){
                f32x4 h = H[m][t];
                h = __builtin_amdgcn_mfma_f32_16x16x32_bf16(At0, W2f0[t], h, 0, 0, 0);
                h = __builtin_amdgcn_mfma_f32_16x16x32_bf16(At1, W2f1[t], h, 0, 0, 0);
                H[m][t] = h;
            }
        }
    }

    // ---- epilogue: u = H @ W1a^T; butterfly over 16-lane c-groups ----
    float wa0[4], wa1[4], wa2[4];
#pragma unroll
    for (int t = 0; t < 4; t++){
        wa0[t] = W1a[      16*t + c];
        wa1[t] = W1a[ 64 + 16*t + c];
        wa2[t] = W1a[128 + 16*t + c];
    }
    float myu0 = 0.f, myu1 = 0.f, myu2 = 0.f;
#pragma unroll
    for (int m = 0; m < 4; m++){
#pragma unroll
        for (int j = 0; j < 4; j++){
            float p0 = 0.f, p1 = 0.f, p2 = 0.f;
#pragma unroll
            for (int t = 0; t < 4; t++){
                p0 = fmaf(H[m][t][j], wa0[t], p0);
                p1 = fmaf(H[m][t][j], wa1[t], p1);
                p2 = fmaf(H[m][t][j], wa2[t], p2);
            }
#pragma unroll
            for (int msk = 1; msk < 16; msk <<= 1){
                p0 += __shfl_xor(p0, msk, 64);
                p1 += __shfl_xor(p1, msk, 64);
                p2 += __shfl_xor(p2, msk, 64);
            }
            if (c == 4*m + j){ myu0 = p0; myu1 = p1; myu2 = p2; }
        }
    }
    {
        int n = P0 + 16*(c >> 2) + 4*q + (c & 3);
        if (n < N){
            float u0 = tanhf(myu0), u1 = tanhf(myu1), u2 = tanhf(myu2);
            float r0 = u0*W1b[0] + u1*W1b[1] + u2*W1b[2];
            float r1 = u0*W1b[3] + u1*W1b[4] + u2*W1b[5];
            float r2 = u0*W1b[6] + u1*W1b[7] + u2*W1b[8];
            float px = pos[n*3+0], py = pos[n*3+1], pz = pos[n*3+2];
            float pdx = px + r0, pdy = py + r1, pdz = pz + r2;
            const float* Rb = Rm + b*9;
            float q0 = pdx*Rb[0] + pdy*Rb[3] + pdz*Rb[6];
            float q1 = pdx*Rb[1] + pdy*Rb[4] + pdz*Rb[7];
            size_t base = (size_t)b*N + n;
            out_res[base*3+0] = r0;  out_res[base*3+1] = r1;  out_res[base*3+2] = r2;
            out_pos_d[base*3+0] = pdx; out_pos_d[base*3+1] = pdy; out_pos_d[base*3+2] = pdz;
            out_proj_pos[base*2+0] = q0; out_proj_pos[base*2+1] = q1;
        }
    }
}

// ---------------- bilinear splat with LDS privatization --------------------
__launch_bounds__(256)
__global__ void splat_kernel(const float* __restrict__ proj_pos,
                             const float* __restrict__ ampvar,
                             const float* __restrict__ amp,
                             float* __restrict__ proj_im, int N)
{
    __shared__ float tile[2*TS*TS];
    int b = blockIdx.y;
    for (int i = threadIdx.x; i < 2*TS*TS; i += 256) tile[i] = 0.f;
    __syncthreads();

    float ampv = amp[0];
    int n0 = blockIdx.x * NPTS_PER_BLOCK;
    int n1 = min(n0 + NPTS_PER_BLOCK, N);
    for (int n = n0 + (int)threadIdx.x; n < n1; n += 256){
        size_t base = (size_t)b*N + n;
        float cy = proj_pos[base*2+0];
        float cx = proj_pos[base*2+1];
        float e0 = expf(ampvar[n]);
        float e1 = expf(ampvar[N+n]);
        float inv = ampv / (e0 + e1);
        float v0 = e0*inv, v1 = e1*inv;
        float pyf = (cy + 0.5f) * 255.0f;
        float pxf = (cx + 0.5f) * 255.0f;
        float fy0 = floorf(pyf), fx0 = floorf(pxf);
        int iy = (int)fy0, ix = (int)fx0;
        float fy = pyf - fy0, fx = pxf - fx0;
        float wy[2] = {1.f - fy, fy};
        float wx[2] = {1.f - fx, fx};
#pragma unroll
        for (int dy = 0; dy < 2; dy++){
#pragma unroll
            for (int dx = 0; dx < 2; dx++){
                float w = wy[dy]*wx[dx];
                int yi = min(max(iy+dy, 0), 255);
                int xi = min(max(ix+dx, 0), 255);
                int ty = yi - TO, tx = xi - TO;
                if ((unsigned)ty < TS && (unsigned)tx < TS){
                    atomicAdd(&tile[ty*TS + tx],        v0*w);
                    atomicAdd(&tile[TS*TS + ty*TS + tx], v1*w);
                } else {
                    atomicAdd(&proj_im[((size_t)(b*2+0)*256 + yi)*256 + xi], v0*w);
                    atomicAdd(&proj_im[((size_t)(b*2+1)*256 + yi)*256 + xi], v1*w);
                }
            }
        }
    }
    __syncthreads();
    for (int i = threadIdx.x; i < TS*TS; i += 256){
        int ty = i >> 4, tx = i & (TS-1);
        float v = tile[i];
        if (v != 0.f) atomicAdd(&proj_im[((size_t)(b*2+0)*256 + TO+ty)*256 + TO+tx], v);
        v = tile[TS*TS + i];
        if (v != 0.f) atomicAdd(&proj_im[((size_t)(b*2+1)*256 + TO+ty)*256 + TO+tx], v);
    }
}

// ---------------- DFT pass 1: rows, sparse-aware (nonzero bitmask) ---------
__launch_bounds__(256)
__global__ void dft_rows_kernel(const float* __restrict__ proj_im, float2* __restrict__ S)
{
    int b = blockIdx.y, y = blockIdx.x;
    __shared__ float2 row[256];
    __shared__ unsigned long long nzm[4];
    int k = threadIdx.x;
    const float* im0 = proj_im + ((size_t)(b*2+0)*256 + y)*256;
    const float* im1 = proj_im + ((size_t)(b*2+1)*256 + y)*256;
    float2 my = make_float2(im0[k], im1[k]);
    row[k] = my;
    unsigned long long bal = __ballot(my.x != 0.f || my.y != 0.f);
    if ((k & 63) == 0) nzm[k >> 6] = bal;
    __syncthreads();

    const float w = -6.283185307179586f / 256.0f;
    float2 acc = make_float2(0.f, 0.f);
#pragma unroll 1
    for (int g = 0; g < 4; g++){
        unsigned long long mm = nzm[g];
        while (mm){
            int x = (g << 6) + __ffsll((long long)mm) - 1;
            mm &= mm - 1;
            float2 zv = row[x];
            float s, c;
            sincosf(w * (float)((k * x) & 255), &s, &c);
            acc.x = fmaf(zv.x, c, fmaf(-zv.y, s, acc.x));
            acc.y = fmaf(zv.x, s, fmaf( zv.y, c, acc.y));
        }
    }
    S[((size_t)b*256 + y)*256 + k] = acc;
}

// ---------------- DFT pass 2: column-tile slab, sparse rows, IN PLACE ------
// Block (kxt, b) owns columns [16*kxt, 16*kxt+16). Stage the slab to LDS
// (coalesced 128B runs), flag rows nonzero WITHIN the slab (rows zero in our
// columns contribute exactly zero to our outputs -> skippable, exact, no
// cross-tile info), compact deterministically, accumulate, write in place.
__launch_bounds__(256)
__global__ void dft_cols_kernel(float2* __restrict__ S)
{
    __shared__ float2 slab[256][KXT + 1];   // +1 pad: flag-scan bank spread
    __shared__ unsigned long long wmask[4];
    __shared__ int rows[256];
    __shared__ int nrows_s;
    int b = blockIdx.y, kx0 = blockIdx.x * KXT;
    int tid = threadIdx.x;
    float2* Sb = S + (size_t)b*65536;

    // stage slab: 16 rounds x (16 rows x 16 cols)
#pragma unroll 1
    for (int r0 = 0; r0 < 256; r0 += 16){
        int y = r0 + (tid >> 4), j = tid & 15;
        slab[y][j] = Sb[(size_t)y*256 + kx0 + j];
    }
    __syncthreads();

    // per-row nonzero flag within slab
    bool nz = false;
#pragma unroll
    for (int j = 0; j < KXT; j++){
        float2 v = slab[tid][j];
        nz = nz || (v.x != 0.f) || (v.y != 0.f);
    }
    unsigned long long m = __ballot(nz);
    int wv = tid >> 6, lane = tid & 63;
    if (lane == 0) wmask[wv] = m;
    __syncthreads();
    if (nz){
        int off = 0;
        for (int w2 = 0; w2 < 4; w2++) if (w2 < wv) off += __popcll(wmask[w2]);
        unsigned long long below = (lane == 0) ? 0ULL : (m & ((1ULL << lane) - 1ULL));
        off += __popcll(below);
        rows[off] = tid;
    }
    if (tid == 0){
        int n = 0;
        for (int w2 = 0; w2 < 4; w2++) n += __popcll(wmask[w2]);
        nrows_s = n;
    }
    __syncthreads();
    int nr = nrows_s;

    const float w = -6.283185307179586f / 256.0f;
    int ky = tid;
    float2 acc[KXT];
#pragma unroll
    for (int j = 0; j < KXT; j++) acc[j] = make_float2(0.f, 0.f);
#pragma unroll 1
    for (int r = 0; r < nr; r++){
        int y = rows[r];                       // LDS broadcast
        float s, c;
        sincosf(w * (float)((ky * y) & 255), &s, &c);
#pragma unroll
        for (int j = 0; j < KXT; j++){
            float2 zv = slab[y][j];            // broadcast
            acc[j].x = fmaf(zv.x, c, fmaf(-zv.y, s, acc[j].x));
            acc[j].y = fmaf(zv.x, s, fmaf( zv.y, c, acc[j].y));
        }
    }
    // write in place: our block is the only reader/writer of these columns,
    // and all global reads happened during staging.
#pragma unroll
    for (int j = 0; j < KXT; j++)
        Sb[(size_t)ky*256 + kx0 + j] = acc[j];   // Z[b][ky][kx]
}

// ---------------- Hermitian unpack + CTF filter + channel sum --------------
__launch_bounds__(256)
__global__ void combine_kernel(const float2* __restrict__ Z,
                               const float* __restrict__ A, const float* __restrict__ Bc,
                               float* __restrict__ outP, int pairs)
{
    int gid = blockIdx.x*256 + threadIdx.x;
    int b = gid >> 16;
    int lin = gid & 65535;
    int ky = lin >> 8, kx = lin & 255;
    int mky = (256 - ky) & 255, mkx = (256 - kx) & 255;
    int mlin = mky*256 + mkx;
    if (lin > mlin) return;   // pair owner only
    const float2* Zb = Z + (size_t)b*65536;
    float2 Zk = Zb[lin];
    float2 Zm = Zb[mlin];
    float Er = 0.5f*(Zk.x + Zm.x), Ei = 0.5f*(Zk.y - Zm.y);
    float Or = 0.5f*(Zk.y + Zm.y), Oi = 0.5f*(Zm.x - Zk.x);
    float fy = (ky < 128) ? (float)ky : (float)(ky - 256);
    float fx = (kx < 128) ? (float)kx : (float)(kx - 256);
    float rad = rintf(sqrtf(fy*fy + fx*fx));
    float a0 = A[0], a1 = A[1], b0 = Bc[0], b1 = Bc[1];
    float F0 = a0*a0*expf(-b0*b0*rad);
    float F1 = a1*a1*expf(-b1*b1*rad);
    float2 P = make_float2(fmaf(F0, Er, F1*Or), fmaf(F0, Ei, F1*Oi));
    if (pairs){
        float2* O = (float2*)outP + (size_t)b*65536;
        O[lin] = P;
        if (mlin != lin) O[mlin] = make_float2(P.x, -P.y);
    } else {
        float* O = outP + (size_t)b*65536;
        O[lin] = P.x;
        if (mlin != lin) O[mlin] = P.x;
    }
}

extern "C" void kernel_launch(void* const* d_in, const int* in_sizes, int n_in,
                              void* d_out, int out_size, void* d_ws, size_t ws_size,
                              hipStream_t stream)
{
    const float* z      = (const float*)d_in[0];
    const float* r      = (const float*)d_in[1];
    const float* pos    = (const float*)d_in[2];
    const float* amp    = (const float*)d_in[3];
    const float* ampvar = (const float*)d_in[4];
    const float* W0     = (const float*)d_in[5];
    const float* Wres1  = (const float*)d_in[6];
    const float* Wres2  = (const float*)d_in[7];
    const float* W1a    = (const float*)d_in[8];
    const float* W1b    = (const float*)d_in[9];
    const float* A      = (const float*)d_in[10];
    const float* Bc     = (const float*)d_in[11];

    int B = in_sizes[0] / 16;     // 16
    int N = in_sizes[2] / 3;      // 20000

    size_t nIm = (size_t)B * 65536;
    long long tailSz   = (long long)(2*nIm) + 8LL*B*N;
    long long projSize = (long long)out_size - tailSz;
    int pairs = (projSize >= (long long)(2*nIm)) ? 1 : 0;

    float* out = (float*)d_out;
    float* out_proj    = out;
    float* out_projim  = out + projSize;
    float* out_projpos = out_projim + 2*nIm;          // B*N*2
    float* out_posd    = out_projpos + (size_t)B*N*2; // B*N*3
    float* out_res     = out_posd    + (size_t)B*N*3; // B*N*3

    float* scratch = out_proj;   // dead until dft_rows; decoder consumes first

    float2* S;
    if (pairs)                                         S = (float2*)out_proj;
    else if (ws_size >= (size_t)(2*nIm)*sizeof(float)) S = (float2*)d_ws;
    else                                               S = (float2*)out_proj;

    int n4 = (int)(2*nIm/4);
    zero_kernel<<<(n4 + 255)/256, 256, 0, stream>>>((float4*)out_projim, n4);

    setup_kernel<<<17, 256, 0, stream>>>(r, z, W0, Wres1, Wres2, scratch, B);

    dim3 dgrid((N + 255)/256, B);
    decoder_kernel<<<dgrid, 256, 0, stream>>>(pos, W0, scratch, W1a, W1b,
                                              out_projpos, out_posd, out_res, N);

    dim3 sgrid((N + NPTS_PER_BLOCK - 1)/NPTS_PER_BLOCK, B);
    splat_kernel<<<sgrid, 256, 0, stream>>>(out_projpos, ampvar, amp, out_projim, N);

    dim3 fgrid(256, B);
    dft_rows_kernel<<<fgrid, 256, 0, stream>>>(out_projim, S);
    dim3 cgrid(256/KXT, B);
    dft_cols_kernel<<<cgrid, 256, 0, stream>>>(S);
    combine_kernel<<<(int)(nIm/256), 256, 0, stream>>>(S, A, Bc, out_proj, pairs);
}

// Round 8
// 114.613 us; speedup vs baseline: 4.1861x; 1.0252x over previous
//
#include <hip/hip_runtime.h>
#include <math.h>

#define NPTS_PER_BLOCK 2048
#define TS 16
#define TO 120
#define KXT 16

typedef __attribute__((ext_vector_type(8))) short bf16x8;
typedef __attribute__((ext_vector_type(4))) float f32x4;
typedef __attribute__((ext_vector_type(4))) unsigned int u32x4;

// float -> bf16 bits, round-nearest-even (software; setup only)
__device__ __forceinline__ unsigned short f2bf(float f){
    unsigned u = __float_as_uint(f);
    unsigned r = u + 0x7FFFu + ((u >> 16) & 1u);
    return (unsigned short)(r >> 16);
}
// HW packed f32x2 -> bf16x2 (RNE), gfx950. dst.lo = cvt(src0), dst.hi = cvt(src1)
__device__ __forceinline__ unsigned pk_bf16(float lo, float hi){
    unsigned d;
    asm("v_cvt_pk_bf16_f32 %0, %1, %2" : "=v"(d) : "v"(lo), "v"(hi));
    return d;
}
__device__ __forceinline__ bf16x8 bc(u32x4 v){
    return __builtin_bit_cast(bf16x8, v);
}

// ---------------- zero a float4-aligned region -----------------------------
__global__ void zero_kernel(float4* __restrict__ p, int n4)
{
    int i = blockIdx.x * blockDim.x + threadIdx.x;
    if (i < n4) p[i] = make_float4(0.f, 0.f, 0.f, 0.f);
}

// ---------------- setup: euler, z-contribution, permuted bf16 weights ------
// scratch (floats): Rm @0 (B*9), zc @256 (B*64), Wbf @1280 (32768 ushorts)
// Weights k-PERMUTED for the transposed-MFMA chain:
//   slot s6 (0..63): u=s6>>5, s=s6&31, qh=s>>3, th=(s>>2)&1, jh=s&3
//   feature f = 32u + 16th + 4qh + jh ;  Wp[out][s6] = W[out][f]
// grid: 17 blocks. Block 0: Rm+zc. Blocks 1..16: 1024 weight entries each.
__global__ void setup_kernel(const float* __restrict__ r, const float* __restrict__ z,
                             const float* __restrict__ W0,
                             const float* __restrict__ Wres1,
                             const float* __restrict__ Wres2,
                             float* __restrict__ scratch, int B)
{
    float* Rm  = scratch;
    float* zc  = scratch + 256;
    unsigned short* W1bf = (unsigned short*)(scratch + 1280);
    unsigned short* W2bf = W1bf + 4*4096;
    int blk = blockIdx.x, tid = threadIdx.x;
    if (blk == 0){
        if (tid < B){
            float a = r[tid*3+0], bb = r[tid*3+1], c = r[tid*3+2];
            float ca = cosf(a), sa = sinf(a);
            float cb = cosf(bb), sb = sinf(bb);
            float cc = cosf(c), sc = sinf(c);
            float* Rb = Rm + tid*9;
            Rb[0] = ca*cb*cc - sa*sc;  Rb[1] = -ca*cb*sc - sa*cc;  Rb[2] = ca*sb;
            Rb[3] = sa*cb*cc + ca*sc;  Rb[4] = -sa*cb*sc + ca*cc;  Rb[5] = sa*sb;
            Rb[6] = -sb*cc;            Rb[7] = sb*sc;              Rb[8] = cb;
        }
        for (int e = tid; e < B*64; e += 256){
            int b = e >> 6, i = e & 63;
            float acc = 0.f;
            for (int j = 0; j < 16; j++) acc = fmaf(W0[i*19+3+j], z[b*16+j], acc);
            zc[e] = acc;
        }
    } else {
        int base = (blk - 1) * 1024;
        for (int e = base + tid; e < base + 1024; e += 256){
            int l = e >> 12, rem = e & 4095, orow = rem >> 6, s6 = rem & 63;
            int u = s6 >> 5, s = s6 & 31;
            int f = 32*u + 16*((s >> 2) & 1) + 4*(s >> 3) + (s & 3);
            int src = l*4096 + orow*64 + f;
            W1bf[e] = f2bf(Wres1[src]);
            W2bf[e] = f2bf(Wres2[src]);
        }
    }
}

// ---------------- register-resident MFMA residual-MLP decoder --------------
// 4 waves/block, 64 points/wave (4 point-tiles m of 16). Hidden state kept
// TRANSPOSED in fp32 D-layout registers the whole time:
//   lane 16q+c, tile m, reg [t][j] <-> H[feature 16t+4q+j][point P0+16m+c]
// Every GEMM is computed transposed: D = mfma(A=weight rows, B=H^T), whose
// D-layout IS the next B-operand layout under the fixed k-permutation baked
// into the weights by setup. No LDS, no barriers, no transposes.
__launch_bounds__(256, 1)
__global__ void decoder_kernel(const float* __restrict__ pos,
                               const float* __restrict__ W0,
                               const float* __restrict__ scratch,
                               const float* __restrict__ W1a,
                               const float* __restrict__ W1b,
                               float* __restrict__ out_proj_pos,
                               float* __restrict__ out_pos_d,
                               float* __restrict__ out_res,
                               int N)
{
    const float* __restrict__ Rm = scratch;
    const float* __restrict__ zc = scratch + 256;
    const unsigned short* __restrict__ W1bf = (const unsigned short*)(scratch + 1280);
    const unsigned short* __restrict__ W2bf = W1bf + 4*4096;

    int b  = blockIdx.y;
    int wv = threadIdx.x >> 6;
    int l  = threadIdx.x & 63;
    int q  = l >> 4, c = l & 15;
    int P0 = blockIdx.x * 256 + wv * 64;

    // ---- point coords for my column c of each tile m ----
    float px[4], py[4], pz[4];
#pragma unroll
    for (int m = 0; m < 4; m++){
        int n = P0 + 16*m + c; if (n > N-1) n = N-1;
        px[m] = pos[n*3+0]; py[m] = pos[n*3+1]; pz[m] = pos[n*3+2];
    }

    // ---- H0^T = zc[b] + W0[:, :3] @ pos^T  (fp32, transposed D-layout) ----
    f32x4 H[4][4];   // [m][t], vector lane j
#pragma unroll
    for (int t = 0; t < 4; t++)
#pragma unroll
        for (int j = 0; j < 4; j++){
            int f = 16*t + 4*q + j;
            float zcf = zc[b*64 + f];
            float wx = W0[f*19+0], wy = W0[f*19+1], wz = W0[f*19+2];
#pragma unroll
            for (int m = 0; m < 4; m++)
                H[m][t][j] = fmaf(wz, pz[m], fmaf(wy, py[m], fmaf(wx, px[m], zcf)));
        }

#pragma unroll 1
    for (int ly = 0; ly < 4; ly++){
        const unsigned short* __restrict__ w1l = W1bf + ly*4096;
        const unsigned short* __restrict__ w2l = W2bf + ly*4096;

        // weight A-frags (row p = c), reused across the 4 point-tiles
        bf16x8 W1f[4][2], W2f[4][2];
#pragma unroll
        for (int t = 0; t < 4; t++)
#pragma unroll
            for (int u = 0; u < 2; u++){
                W1f[t][u] = *(const bf16x8*)(w1l + (16*t + c)*64 + 32*u + 8*q);
                W2f[t][u] = *(const bf16x8*)(w2l + (16*t + c)*64 + 32*u + 8*q);
            }

#pragma unroll
        for (int m = 0; m < 4; m++){
            // B-frags from H[m] (registers -> bf16, k-order matches pi)
            u32x4 hb0, hb1;
            hb0.x = pk_bf16(H[m][0][0], H[m][0][1]);
            hb0.y = pk_bf16(H[m][0][2], H[m][0][3]);
            hb0.z = pk_bf16(H[m][1][0], H[m][1][1]);
            hb0.w = pk_bf16(H[m][1][2], H[m][1][3]);
            hb1.x = pk_bf16(H[m][2][0], H[m][2][1]);
            hb1.y = pk_bf16(H[m][2][2], H[m][2][3]);
            hb1.z = pk_bf16(H[m][3][0], H[m][3][1]);
            hb1.w = pk_bf16(H[m][3][2], H[m][3][3]);
            bf16x8 B0 = bc(hb0), B1 = bc(hb1);

            // S^T = W1 @ H^T
            f32x4 S[4];
#pragma unroll
            for (int t = 0; t < 4; t++){
                f32x4 s = {0.f, 0.f, 0.f, 0.f};
                s = __builtin_amdgcn_mfma_f32_16x16x32_bf16(W1f[t][0], B0, s, 0, 0, 0);
                s = __builtin_amdgcn_mfma_f32_16x16x32_bf16(W1f[t][1], B1, s, 0, 0, 0);
                S[t] = s;
            }

            // relu + pack
            u32x4 sb0, sb1;
            sb0.x = pk_bf16(fmaxf(S[0][0],0.f), fmaxf(S[0][1],0.f));
            sb0.y = pk_bf16(fmaxf(S[0][2],0.f), fmaxf(S[0][3],0.f));
            sb0.z = pk_bf16(fmaxf(S[1][0],0.f), fmaxf(S[1][1],0.f));
            sb0.w = pk_bf16(fmaxf(S[1][2],0.f), fmaxf(S[1][3],0.f));
            sb1.x = pk_bf16(fmaxf(S[2][0],0.f), fmaxf(S[2][1],0.f));
            sb1.y = pk_bf16(fmaxf(S[2][2],0.f), fmaxf(S[2][3],0.f));
            sb1.z = pk_bf16(fmaxf(S[3][0],0.f), fmaxf(S[3][1],0.f));
            sb1.w = pk_bf16(fmaxf(S[3][2],0.f), fmaxf(S[3][3],0.f));
            bf16x8 T0 = bc(sb0), T1 = bc(sb1);

            // H^T += W2 @ relu(S)^T  (accumulate into fp32 residual stream)
#pragma unroll
            for (int t = 0; t < 4; t++){
                f32x4 h = H[m][t];
                h = __builtin_amdgcn_mfma_f32_16x16x32_bf16(W2f[t][0], T0, h, 0, 0, 0);
                h = __builtin_amdgcn_mfma_f32_16x16x32_bf16(W2f[t][1], T1, h, 0, 0, 0);
                H[m][t] = h;
            }
        }
    }

    // ---- epilogue: u_a[point] = sum_f W1a[a][f] * H^T[f][point] ----
    // lane partial over its 16 features, then butterfly over the 4 q-groups.
    float4 fa0[4], fa1[4], fa2[4];
#pragma unroll
    for (int t = 0; t < 4; t++){
        fa0[t] = *(const float4*)(W1a +       16*t + 4*q);
        fa1[t] = *(const float4*)(W1a +  64 + 16*t + 4*q);
        fa2[t] = *(const float4*)(W1a + 128 + 16*t + 4*q);
    }
    float u0 = 0.f, u1 = 0.f, u2 = 0.f;
#pragma unroll
    for (int m = 0; m < 4; m++){
        float p0 = 0.f, p1 = 0.f, p2 = 0.f;
#pragma unroll
        for (int t = 0; t < 4; t++){
            p0 = fmaf(H[m][t][0], fa0[t].x, p0); p0 = fmaf(H[m][t][1], fa0[t].y, p0);
            p0 = fmaf(H[m][t][2], fa0[t].z, p0); p0 = fmaf(H[m][t][3], fa0[t].w, p0);
            p1 = fmaf(H[m][t][0], fa1[t].x, p1); p1 = fmaf(H[m][t][1], fa1[t].y, p1);
            p1 = fmaf(H[m][t][2], fa1[t].z, p1); p1 = fmaf(H[m][t][3], fa1[t].w, p1);
            p2 = fmaf(H[m][t][0], fa2[t].x, p2); p2 = fmaf(H[m][t][1], fa2[t].y, p2);
            p2 = fmaf(H[m][t][2], fa2[t].z, p2); p2 = fmaf(H[m][t][3], fa2[t].w, p2);
        }
        p0 += __shfl_xor(p0, 16, 64); p0 += __shfl_xor(p0, 32, 64);
        p1 += __shfl_xor(p1, 16, 64); p1 += __shfl_xor(p1, 32, 64);
        p2 += __shfl_xor(p2, 16, 64); p2 += __shfl_xor(p2, 32, 64);
        if (q == m){ u0 = p0; u1 = p1; u2 = p2; }
    }

    {
        int n = P0 + 16*q + c;
        if (n < N){
            float pxs = (q==0)?px[0]:(q==1)?px[1]:(q==2)?px[2]:px[3];
            float pys = (q==0)?py[0]:(q==1)?py[1]:(q==2)?py[2]:py[3];
            float pzs = (q==0)?pz[0]:(q==1)?pz[1]:(q==2)?pz[2]:pz[3];
            float t0 = tanhf(u0), t1 = tanhf(u1), t2 = tanhf(u2);
            float r0 = t0*W1b[0] + t1*W1b[1] + t2*W1b[2];
            float r1 = t0*W1b[3] + t1*W1b[4] + t2*W1b[5];
            float r2 = t0*W1b[6] + t1*W1b[7] + t2*W1b[8];
            float pdx = pxs + r0, pdy = pys + r1, pdz = pzs + r2;
            const float* Rb = Rm + b*9;
            float q0 = pdx*Rb[0] + pdy*Rb[3] + pdz*Rb[6];
            float q1 = pdx*Rb[1] + pdy*Rb[4] + pdz*Rb[7];
            size_t base = (size_t)b*N + n;
            out_res[base*3+0] = r0;  out_res[base*3+1] = r1;  out_res[base*3+2] = r2;
            out_pos_d[base*3+0] = pdx; out_pos_d[base*3+1] = pdy; out_pos_d[base*3+2] = pdz;
            out_proj_pos[base*2+0] = q0; out_proj_pos[base*2+1] = q1;
        }
    }
}

// ---------------- bilinear splat with LDS privatization --------------------
__launch_bounds__(256)
__global__ void splat_kernel(const float* __restrict__ proj_pos,
                             const float* __restrict__ ampvar,
                             const float* __restrict__ amp,
                             float* __restrict__ proj_im, int N)
{
    __shared__ float tile[2*TS*TS];
    int b = blockIdx.y;
    for (int i = threadIdx.x; i < 2*TS*TS; i += 256) tile[i] = 0.f;
    __syncthreads();

    float ampv = amp[0];
    int n0 = blockIdx.x * NPTS_PER_BLOCK;
    int n1 = min(n0 + NPTS_PER_BLOCK, N);
    for (int n = n0 + (int)threadIdx.x; n < n1; n += 256){
        size_t base = (size_t)b*N + n;
        float cy = proj_pos[base*2+0];
        float cx = proj_pos[base*2+1];
        float e0 = expf(ampvar[n]);
        float e1 = expf(ampvar[N+n]);
        float inv = ampv / (e0 + e1);
        float v0 = e0*inv, v1 = e1*inv;
        float pyf = (cy + 0.5f) * 255.0f;
        float pxf = (cx + 0.5f) * 255.0f;
        float fy0 = floorf(pyf), fx0 = floorf(pxf);
        int iy = (int)fy0, ix = (int)fx0;
        float fy = pyf - fy0, fx = pxf - fx0;
        float wy[2] = {1.f - fy, fy};
        float wx[2] = {1.f - fx, fx};
#pragma unroll
        for (int dy = 0; dy < 2; dy++){
#pragma unroll
            for (int dx = 0; dx < 2; dx++){
                float w = wy[dy]*wx[dx];
                int yi = min(max(iy+dy, 0), 255);
                int xi = min(max(ix+dx, 0), 255);
                int ty = yi - TO, tx = xi - TO;
                if ((unsigned)ty < TS && (unsigned)tx < TS){
                    atomicAdd(&tile[ty*TS + tx],        v0*w);
                    atomicAdd(&tile[TS*TS + ty*TS + tx], v1*w);
                } else {
                    atomicAdd(&proj_im[((size_t)(b*2+0)*256 + yi)*256 + xi], v0*w);
                    atomicAdd(&proj_im[((size_t)(b*2+1)*256 + yi)*256 + xi], v1*w);
                }
            }
        }
    }
    __syncthreads();
    for (int i = threadIdx.x; i < TS*TS; i += 256){
        int ty = i >> 4, tx = i & (TS-1);
        float v = tile[i];
        if (v != 0.f) atomicAdd(&proj_im[((size_t)(b*2+0)*256 + TO+ty)*256 + TO+tx], v);
        v = tile[TS*TS + i];
        if (v != 0.f) atomicAdd(&proj_im[((size_t)(b*2+1)*256 + TO+ty)*256 + TO+tx], v);
    }
}

// ---------------- DFT pass 1: rows, sparse-aware (nonzero bitmask) ---------
__launch_bounds__(256)
__global__ void dft_rows_kernel(const float* __restrict__ proj_im, float2* __restrict__ S)
{
    int b = blockIdx.y, y = blockIdx.x;
    __shared__ float2 row[256];
    __shared__ unsigned long long nzm[4];
    int k = threadIdx.x;
    const float* im0 = proj_im + ((size_t)(b*2+0)*256 + y)*256;
    const float* im1 = proj_im + ((size_t)(b*2+1)*256 + y)*256;
    float2 my = make_float2(im0[k], im1[k]);
    row[k] = my;
    unsigned long long bal = __ballot(my.x != 0.f || my.y != 0.f);
    if ((k & 63) == 0) nzm[k >> 6] = bal;
    __syncthreads();

    const float w = -6.283185307179586f / 256.0f;
    float2 acc = make_float2(0.f, 0.f);
#pragma unroll 1
    for (int g = 0; g < 4; g++){
        unsigned long long mm = nzm[g];
        while (mm){
            int x = (g << 6) + __ffsll((long long)mm) - 1;
            mm &= mm - 1;
            float2 zv = row[x];
            float s, c;
            sincosf(w * (float)((k * x) & 255), &s, &c);
            acc.x = fmaf(zv.x, c, fmaf(-zv.y, s, acc.x));
            acc.y = fmaf(zv.x, s, fmaf( zv.y, c, acc.y));
        }
    }
    S[((size_t)b*256 + y)*256 + k] = acc;
}

// ---------------- DFT pass 2: column-tile slab, sparse rows, IN PLACE ------
__launch_bounds__(256)
__global__ void dft_cols_kernel(float2* __restrict__ S)
{
    __shared__ float2 slab[256][KXT + 1];
    __shared__ unsigned long long wmask[4];
    __shared__ int rows[256];
    __shared__ int nrows_s;
    int b = blockIdx.y, kx0 = blockIdx.x * KXT;
    int tid = threadIdx.x;
    float2* Sb = S + (size_t)b*65536;

#pragma unroll 1
    for (int r0 = 0; r0 < 256; r0 += 16){
        int y = r0 + (tid >> 4), j = tid & 15;
        slab[y][j] = Sb[(size_t)y*256 + kx0 + j];
    }
    __syncthreads();

    bool nz = false;
#pragma unroll
    for (int j = 0; j < KXT; j++){
        float2 v = slab[tid][j];
        nz = nz || (v.x != 0.f) || (v.y != 0.f);
    }
    unsigned long long m = __ballot(nz);
    int wv = tid >> 6, lane = tid & 63;
    if (lane == 0) wmask[wv] = m;
    __syncthreads();
    if (nz){
        int off = 0;
        for (int w2 = 0; w2 < 4; w2++) if (w2 < wv) off += __popcll(wmask[w2]);
        unsigned long long below = (lane == 0) ? 0ULL : (m & ((1ULL << lane) - 1ULL));
        off += __popcll(below);
        rows[off] = tid;
    }
    if (tid == 0){
        int n = 0;
        for (int w2 = 0; w2 < 4; w2++) n += __popcll(wmask[w2]);
        nrows_s = n;
    }
    __syncthreads();
    int nr = nrows_s;

    const float w = -6.283185307179586f / 256.0f;
    int ky = tid;
    float2 acc[KXT];
#pragma unroll
    for (int j = 0; j < KXT; j++) acc[j] = make_float2(0.f, 0.f);
#pragma unroll 1
    for (int r = 0; r < nr; r++){
        int y = rows[r];
        float s, c;
        sincosf(w * (float)((ky * y) & 255), &s, &c);
#pragma unroll
        for (int j = 0; j < KXT; j++){
            float2 zv = slab[y][j];
            acc[j].x = fmaf(zv.x, c, fmaf(-zv.y, s, acc[j].x));
            acc[j].y = fmaf(zv.x, s, fmaf( zv.y, c, acc[j].y));
        }
    }
#pragma unroll
    for (int j = 0; j < KXT; j++)
        Sb[(size_t)ky*256 + kx0 + j] = acc[j];   // Z[b][ky][kx]
}

// ---------------- Hermitian unpack + CTF filter + channel sum --------------
__launch_bounds__(256)
__global__ void combine_kernel(const float2* __restrict__ Z,
                               const float* __restrict__ A, const float* __restrict__ Bc,
                               float* __restrict__ outP, int pairs)
{
    int gid = blockIdx.x*256 + threadIdx.x;
    int b = gid >> 16;
    int lin = gid & 65535;
    int ky = lin >> 8, kx = lin & 255;
    int mky = (256 - ky) & 255, mkx = (256 - kx) & 255;
    int mlin = mky*256 + mkx;
    if (lin > mlin) return;   // pair owner only
    const float2* Zb = Z + (size_t)b*65536;
    float2 Zk = Zb[lin];
    float2 Zm = Zb[mlin];
    float Er = 0.5f*(Zk.x + Zm.x), Ei = 0.5f*(Zk.y - Zm.y);
    float Or = 0.5f*(Zk.y + Zm.y), Oi = 0.5f*(Zm.x - Zk.x);
    float fy = (ky < 128) ? (float)ky : (float)(ky - 256);
    float fx = (kx < 128) ? (float)kx : (float)(kx - 256);
    float rad = rintf(sqrtf(fy*fy + fx*fx));
    float a0 = A[0], a1 = A[1], b0 = Bc[0], b1 = Bc[1];
    float F0 = a0*a0*expf(-b0*b0*rad);
    float F1 = a1*a1*expf(-b1*b1*rad);
    float2 P = make_float2(fmaf(F0, Er, F1*Or), fmaf(F0, Ei, F1*Oi));
    if (pairs){
        float2* O = (float2*)outP + (size_t)b*65536;
        O[lin] = P;
        if (mlin != lin) O[mlin] = make_float2(P.x, -P.y);
    } else {
        float* O = outP + (size_t)b*65536;
        O[lin] = P.x;
        if (mlin != lin) O[mlin] = P.x;
    }
}

extern "C" void kernel_launch(void* const* d_in, const int* in_sizes, int n_in,
                              void* d_out, int out_size, void* d_ws, size_t ws_size,
                              hipStream_t stream)
{
    const float* z      = (const float*)d_in[0];
    const float* r      = (const float*)d_in[1];
    const float* pos    = (const float*)d_in[2];
    const float* amp    = (const float*)d_in[3];
    const float* ampvar = (const float*)d_in[4];
    const float* W0     = (const float*)d_in[5];
    const float* Wres1  = (const float*)d_in[6];
    const float* Wres2  = (const float*)d_in[7];
    const float* W1a    = (const float*)d_in[8];
    const float* W1b    = (const float*)d_in[9];
    const float* A      = (const float*)d_in[10];
    const float* Bc     = (const float*)d_in[11];

    int B = in_sizes[0] / 16;     // 16
    int N = in_sizes[2] / 3;      // 20000

    size_t nIm = (size_t)B * 65536;
    long long tailSz   = (long long)(2*nIm) + 8LL*B*N;
    long long projSize = (long long)out_size - tailSz;
    int pairs = (projSize >= (long long)(2*nIm)) ? 1 : 0;

    float* out = (float*)d_out;
    float* out_proj    = out;
    float* out_projim  = out + projSize;
    float* out_projpos = out_projim + 2*nIm;          // B*N*2
    float* out_posd    = out_projpos + (size_t)B*N*2; // B*N*3
    float* out_res     = out_posd    + (size_t)B*N*3; // B*N*3

    float* scratch = out_proj;   // dead until dft_rows; decoder consumes first

    float2* S;
    if (pairs)                                         S = (float2*)out_proj;
    else if (ws_size >= (size_t)(2*nIm)*sizeof(float)) S = (float2*)d_ws;
    else                                               S = (float2*)out_proj;

    int n4 = (int)(2*nIm/4);
    zero_kernel<<<(n4 + 255)/256, 256, 0, stream>>>((float4*)out_projim, n4);

    setup_kernel<<<17, 256, 0, stream>>>(r, z, W0, Wres1, Wres2, scratch, B);

    dim3 dgrid((N + 255)/256, B);
    decoder_kernel<<<dgrid, 256, 0, stream>>>(pos, W0, scratch, W1a, W1b,
                                              out_projpos, out_posd, out_res, N);

    dim3 sgrid((N + NPTS_PER_BLOCK - 1)/NPTS_PER_BLOCK, B);
    splat_kernel<<<sgrid, 256, 0, stream>>>(out_projpos, ampvar, amp, out_projim, N);

    dim3 fgrid(256, B);
    dft_rows_kernel<<<fgrid, 256, 0, stream>>>(out_projim, S);
    dim3 cgrid(256/KXT, B);
    dft_cols_kernel<<<cgrid, 256, 0, stream>>>(S);
    combine_kernel<<<(int)(nIm/256), 256, 0, stream>>>(S, A, Bc, out_proj, pairs);
}